// Round 4
// baseline (283.675 us; speedup 1.0000x reference)
//
#include <hip/hip_runtime.h>

typedef unsigned short u16;
typedef unsigned int u32;
typedef __bf16 bf16x8 __attribute__((ext_vector_type(8)));
typedef float f4_t __attribute__((ext_vector_type(4)));

#define E_DIM 1024
#define L_TOT 4097
#define B_SZ 2
#define M_ROWS 8194   // B*L
#define NWIN 31
#define HHEADS 16
#define GCHUNKS 17    // ceil(4097/256)

__device__ __forceinline__ float b2f(u16 v) {
  union { u32 u; float f; } x; x.u = ((u32)v) << 16; return x.f;
}
__device__ __forceinline__ u16 f2b(float f) {
  union { float f; u32 u; } x; x.f = f;
  u32 r = (x.u + 0x7FFFu + ((x.u >> 16) & 1u)) >> 16;
  return (u16)r;
}
__device__ __forceinline__ f4_t mfma16(bf16x8 a, bf16x8 b, f4_t c) {
  return __builtin_amdgcn_mfma_f32_16x16x32_bf16(a, b, c, 0, 0, 0);
}

// async global->LDS, 16B per lane; LDS dest = wave-uniform base + lane*16
#define GLOAD16(gp, lp)                                                              \
  __builtin_amdgcn_global_load_lds(                                                  \
      (const __attribute__((address_space(1))) u32*)(gp),                            \
      (__attribute__((address_space(3))) u32*)(lp), 16, 0, 0)

// ---------------- fp32 -> bf16 convert (hidden states) ----------------
__global__ __launch_bounds__(256) void cvt_kernel(const float* __restrict__ src,
                                                  u16* __restrict__ dst, int n4) {
  int i = blockIdx.x * 256 + threadIdx.x;
  if (i >= n4) return;
  float4 v = ((const float4*)src)[i];
  u16 o[4] = {f2b(v.x), f2b(v.y), f2b(v.z), f2b(v.w)};
  *(uint2*)(dst + (size_t)i * 4) = *(uint2*)o;
}

// ---------------- weight transpose + convert: W (K x N) -> Wt (N x K) bf16 ----------------
__global__ __launch_bounds__(256) void wtrans_kernel(const float* __restrict__ w0,
                                                     const float* __restrict__ w1,
                                                     const float* __restrict__ w2,
                                                     const float* __restrict__ w3,
                                                     u16* __restrict__ wtb) {
  const float* src = blockIdx.z == 0 ? w0 : blockIdx.z == 1 ? w1 : blockIdx.z == 2 ? w2 : w3;
  u16* dst = wtb + (size_t)blockIdx.z * E_DIM * E_DIM;
  __shared__ float tile[32][33];
  int tx = threadIdx.x, ty = threadIdx.y;
  int x = blockIdx.x * 32 + tx;
  int y0 = blockIdx.y * 32;
  for (int j = ty; j < 32; j += 8) tile[j][tx] = src[(size_t)(y0 + j) * E_DIM + x];
  __syncthreads();
  for (int j = ty; j < 32; j += 8)
    dst[(size_t)(blockIdx.x * 32 + j) * E_DIM + blockIdx.y * 32 + tx] = f2b(tile[tx][j]);
}

// ================= 256x256 8-phase GEMM (T2+T3+T4+T5) =================
// C(M x NTIL*256) = A(M x 1024) * Wt^T + bias. Wt stored [N][1024] (row = out col).
// 512 threads = 8 waves (2M x 4N). BK=64, 2 K-tiles per 8-phase iteration.
// LDS [2 buf][256][64] per operand, XOR swizzle slot^=(row&7): linear dest for
// global_load_lds, inverse-swizzled global source col, swizzled ds_read.
// MODE 0: bf16 demux to 3 tensors [M_ROWS][1024]. MODE 1: fp32 single tensor.
template <int MODE>
__global__ __launch_bounds__(512, 1) void gemm8_kernel(const u16* __restrict__ A,
                                                       const u16* __restrict__ Wt,
                                                       const float* __restrict__ b0,
                                                       const float* __restrict__ b1,
                                                       const float* __restrict__ b2,
                                                       void* __restrict__ outBase,
                                                       int M, int NTIL) {
  __shared__ u16 lA[2][256][64];
  __shared__ u16 lB[2][256][64];

  // bijective XCD swizzle (m204), n-fast for A-panel L2 reuse
  int nwg = gridDim.x;
  int q8 = nwg >> 3, r8 = nwg & 7;
  int orig = blockIdx.x;
  int xcd = orig & 7, loc = orig >> 3;
  int wg = (xcd < r8 ? xcd * (q8 + 1) : r8 * (q8 + 1) + (xcd - r8) * q8) + loc;
  int mt = wg / NTIL, nt = wg - mt * NTIL;
  int m0 = mt * 256, n0 = nt * 256;

  int t = threadIdx.x, lane = t & 63, w = t >> 6;
  int wm = w >> 2, wn = w & 3;
  int lr = lane & 15, g = lane >> 4;

  // ---- staging addressing: thread t loads 16B; phys row = t>>3, phys slot = t&7;
  // source col-slot = (t&7) ^ ((t>>3)&7)  (inverse of read-side swizzle)
  int rsub = t >> 3;
  int ssrc = ((t & 7) ^ (rsub & 7)) * 8;
  const u16* pa[4];
  const u16* pb[4];
#pragma unroll
  for (int q = 0; q < 4; q++) {
    int ra = m0 + q * 64 + rsub;
    if (ra >= M) ra = M - 1;
    pa[q] = A + (size_t)ra * 1024 + ssrc;
    pb[q] = Wt + (size_t)(n0 + q * 64 + rsub) * 1024 + ssrc;
  }
  u16* la = &lA[0][0][0] + w * 512;  // wave-uniform base within quarter
  u16* lb = &lB[0][0][0] + w * 512;

#define SA(bf, q, kt) GLOAD16(pa[q] + (kt) * 64, la + (bf) * 16384 + (q) * 4096)
#define SB(bf, q, kt) GLOAD16(pb[q] + (kt) * 64, lb + (bf) * 16384 + (q) * 4096)

  // frag reads; row & 7 == lr & 7 for all frag rows
#define LDA(bf, MQ, mi, kk) \
  (*(const bf16x8*)(&lA[bf][wm * 128 + (MQ) * 64 + (mi) * 16 + lr][((((kk) * 4 + g)) ^ (lr & 7)) * 8]))
#define LDB(bf, NQ, ni, kk) \
  (*(const bf16x8*)(&lB[bf][wn * 64 + (NQ) * 32 + (ni) * 16 + lr][((((kk) * 4 + g)) ^ (lr & 7)) * 8]))

  f4_t acc[2][4][2][2] = {};  // [MQ][mi][NQ][ni]
  bf16x8 bfr[2][2];           // B frags, reused across the 2 phases of same NQ

#define PHASE(BUF, MQ, NQ, LOADB, STAGES, VMNT)                                   \
  {                                                                               \
    bf16x8 af_[4][2];                                                             \
    _Pragma("unroll") for (int mi_ = 0; mi_ < 4; mi_++) {                         \
      af_[mi_][0] = LDA(BUF, MQ, mi_, 0);                                         \
      af_[mi_][1] = LDA(BUF, MQ, mi_, 1);                                         \
    }                                                                             \
    if (LOADB) {                                                                  \
      _Pragma("unroll") for (int ni_ = 0; ni_ < 2; ni_++) {                       \
        bfr[ni_][0] = LDB(BUF, NQ, ni_, 0);                                       \
        bfr[ni_][1] = LDB(BUF, NQ, ni_, 1);                                       \
      }                                                                           \
    }                                                                             \
    STAGES;                                                                       \
    VMNT;                                                                         \
    __builtin_amdgcn_sched_barrier(0);                                            \
    __builtin_amdgcn_s_barrier();                                                 \
    __builtin_amdgcn_sched_barrier(0);                                            \
    __builtin_amdgcn_s_setprio(1);                                                \
    _Pragma("unroll") for (int mi_ = 0; mi_ < 4; mi_++)                           \
      _Pragma("unroll") for (int ni_ = 0; ni_ < 2; ni_++) {                       \
        acc[MQ][mi_][NQ][ni_] = mfma16(af_[mi_][0], bfr[ni_][0], acc[MQ][mi_][NQ][ni_]); \
        acc[MQ][mi_][NQ][ni_] = mfma16(af_[mi_][1], bfr[ni_][1], acc[MQ][mi_][NQ][ni_]); \
      }                                                                           \
    __builtin_amdgcn_s_setprio(0);                                                \
    __builtin_amdgcn_sched_barrier(0);                                            \
    __builtin_amdgcn_s_barrier();                                                 \
    __builtin_amdgcn_sched_barrier(0);                                            \
  }

  // ---- prologue: tile0 (buf0) fully + tile1 Aq0,Aq2 (buf1); allow last 2 in flight
#pragma unroll
  for (int q = 0; q < 4; q++) SA(0, q, 0);
#pragma unroll
  for (int q = 0; q < 4; q++) SB(0, q, 0);
  SA(1, 0, 1);
  SA(1, 2, 1);
  asm volatile("s_waitcnt vmcnt(2)" ::: "memory");
  __builtin_amdgcn_sched_barrier(0);
  __builtin_amdgcn_s_barrier();
  __builtin_amdgcn_sched_barrier(0);

  // ---- main loop: 16 K-tiles, 2 per iteration
  for (int j = 0; j < 8; j++) {
    int tB = 2 * j + 1, tC = 2 * j + 2, tD = 2 * j + 3;
    bool st = (j < 7);
    // p0: compute t0=2j (buf0) MQ0 NQ0; stage tB.Aq1,Aq3 -> buf1 (retired prev p7)
    PHASE(0, 0, 0, true, { SA(1, 1, tB); SA(1, 3, tB); }, {});
    // p1: MQ1 NQ0; stage tB.Bq0,Bq1
    PHASE(0, 1, 0, false, { SB(1, 0, tB); SB(1, 1, tB); }, {});
    // p2: MQ0 NQ1; stage tB.Bq2,Bq3
    PHASE(0, 0, 1, true, { SB(1, 2, tB); SB(1, 3, tB); }, {});
    // p3: MQ1 NQ1; stage tC.Aq0,Aq2 -> buf0 (q0/q2 retired at p2); verify tB
    PHASE(0, 1, 1, false,
          { if (st) { SA(0, 0, tC); SA(0, 2, tC); } },
          { if (st) { asm volatile("s_waitcnt vmcnt(2)" ::: "memory"); }
            else    { asm volatile("s_waitcnt vmcnt(0)" ::: "memory"); } });
    // p4: compute t1=2j+1 (buf1) MQ0 NQ0; stage tC.Aq1,Aq3 (retired p3)
    PHASE(1, 0, 0, true, { if (st) { SA(0, 1, tC); SA(0, 3, tC); } }, {});
    // p5: MQ1 NQ0; stage tC.Bq0,Bq1 (B retired p3)
    PHASE(1, 1, 0, false, { if (st) { SB(0, 0, tC); SB(0, 1, tC); } }, {});
    // p6: MQ0 NQ1; stage tC.Bq2,Bq3
    PHASE(1, 0, 1, true, { if (st) { SB(0, 2, tC); SB(0, 3, tC); } }, {});
    // p7: MQ1 NQ1; stage tD.Aq0,Aq2 -> buf1 (q0/q2 retired p6); verify tC
    PHASE(1, 1, 1, false,
          { if (st) { SA(1, 0, tD); SA(1, 2, tD); } },
          { if (st) { asm volatile("s_waitcnt vmcnt(2)" ::: "memory"); }
            else    { asm volatile("s_waitcnt vmcnt(0)" ::: "memory"); } });
  }

  // ---- epilogue: direct stores
#pragma unroll
  for (int nq = 0; nq < 2; nq++) {
#pragma unroll
    for (int ni = 0; ni < 2; ni++) {
      int n = n0 + wn * 64 + nq * 32 + ni * 16 + lr;
      if (MODE == 0) {
        int tsel = n >> 10, ncol = n & 1023;
        const float* bp = tsel == 0 ? b0 : (tsel == 1 ? b1 : b2);
        float bb = bp[ncol];
        u16* op = (u16*)outBase + (size_t)tsel * ((size_t)M_ROWS * E_DIM) + ncol;
#pragma unroll
        for (int mq = 0; mq < 2; mq++)
#pragma unroll
          for (int mi = 0; mi < 4; mi++) {
            int mb = m0 + wm * 128 + mq * 64 + mi * 16 + g * 4;
#pragma unroll
            for (int r = 0; r < 4; r++)
              if (mb + r < M) op[(size_t)(mb + r) * E_DIM] = f2b(acc[mq][mi][nq][ni][r] + bb);
          }
      } else {
        float bb = b0[n];
        float* op = (float*)outBase + n;
#pragma unroll
        for (int mq = 0; mq < 2; mq++)
#pragma unroll
          for (int mi = 0; mi < 4; mi++) {
            int mb = m0 + wm * 128 + mq * 64 + mi * 16 + g * 4;
#pragma unroll
            for (int r = 0; r < 4; r++)
              if (mb + r < M) op[(size_t)(mb + r) * E_DIM] = acc[mq][mi][nq][ni][r] + bb;
          }
      }
    }
  }
#undef SA
#undef SB
#undef LDA
#undef LDB
#undef PHASE
}

// ---------------- global attention, phase 1: per-chunk partials ----------------
__global__ __launch_bounds__(256) void gattn1_kernel(const u16* __restrict__ Qb,
                                                     const u16* __restrict__ Kb,
                                                     const u16* __restrict__ Vb,
                                                     float* __restrict__ part) {
  int c = blockIdx.x;
  int h = blockIdx.y;
  int b = blockIdx.z;
  int t = threadIdx.x;
  __shared__ float qsh[64];
  __shared__ float red[4];
  __shared__ float psh[256];
  __shared__ float cred[4][64];

  size_t base = (size_t)b * L_TOT * E_DIM + h * 64;
  if (t < 64) qsh[t] = b2f(Qb[base + t]);
  __syncthreads();

  int row = c * 256 + t;
  bool valid = row < L_TOT;
  float dot = -1e30f;
  if (valid) {
    const u16* kp = Kb + base + (size_t)row * E_DIM;
    float acc = 0.f;
#pragma unroll
    for (int j = 0; j < 64; j += 8) {
      uint4 kv = *(const uint4*)(kp + j);
      const u16* kk = (const u16*)&kv;
#pragma unroll
      for (int q = 0; q < 8; q++) acc += qsh[j + q] * b2f(kk[q]);
    }
    dot = acc * 0.125f;
  }
  float m = dot;
  for (int mask = 1; mask < 64; mask <<= 1) m = fmaxf(m, __shfl_xor(m, mask));
  if ((t & 63) == 0) red[t >> 6] = m;
  __syncthreads();
  m = fmaxf(fmaxf(red[0], red[1]), fmaxf(red[2], red[3]));
  float p = valid ? __expf(dot - m) : 0.f;
  psh[t] = p;
  float s = p;
  for (int mask = 1; mask < 64; mask <<= 1) s += __shfl_xor(s, mask);
  __syncthreads();
  if ((t & 63) == 0) red[t >> 6] = s;
  __syncthreads();
  s = red[0] + red[1] + red[2] + red[3];

  int d = t & 63, gq = t >> 6;
  float acc = 0.f;
#pragma unroll 4
  for (int i = 0; i < 64; i++) {
    int sl = gq * 64 + i;
    int r2 = c * 256 + sl;
    if (r2 < L_TOT) acc += psh[sl] * b2f(Vb[base + (size_t)r2 * E_DIM + d]);
  }
  cred[gq][d] = acc;
  __syncthreads();
  if (t < 64) {
    float v = cred[0][t] + cred[1][t] + cred[2][t] + cred[3][t];
    float* pp = part + (((size_t)(b * HHEADS + h) * GCHUNKS + c) * 66);
    pp[t] = v;
    if (t == 0) { pp[64] = m; pp[65] = s; }
  }
}

// ---------------- global attention, phase 2: combine chunks ----------------
__global__ __launch_bounds__(64) void gattn2_kernel(const float* __restrict__ part,
                                                    u16* __restrict__ ctxb) {
  int bh = blockIdx.x;
  int b = bh >> 4, h = bh & 15;
  int d = threadIdx.x;
  const float* pp = part + ((size_t)(b * HHEADS + h) * GCHUNKS) * 66;
  float m = -1e30f;
#pragma unroll
  for (int c = 0; c < GCHUNKS; c++) m = fmaxf(m, pp[c * 66 + 64]);
  float stot = 0.f, acc = 0.f;
#pragma unroll
  for (int c = 0; c < GCHUNKS; c++) {
    float w = __expf(pp[c * 66 + 64] - m);
    stot += pp[c * 66 + 65] * w;
    acc += pp[c * 66 + d] * w;
  }
  ctxb[(size_t)b * L_TOT * E_DIM + h * 64 + d] = f2b(acc / stot);
}

// ---------------- windowed attention: one block per (w, h, b) ----------------
__global__ __launch_bounds__(256) void wattn_kernel(const u16* __restrict__ Qb,
                                                    const u16* __restrict__ Kb,
                                                    const u16* __restrict__ Vb,
                                                    u16* __restrict__ winctx) {
  int wdw = blockIdx.x;
  int h = blockIdx.y;
  int b = blockIdx.z;

  __shared__ u16 Ks[256][72];
  __shared__ u16 Vt[64][264];
  __shared__ u16 Ps[64][264];
  __shared__ u16 Qs[64][72];
  __shared__ float lsum[64];

  int t = threadIdx.x, lane = t & 63, wv = t >> 6;
  int g = lane >> 4, lr = lane & 15;
  size_t rowbase = (size_t)b * L_TOT + 1 + (size_t)wdw * 128;
  int hoff = h * 64;

#pragma unroll
  for (int pass = 0; pass < 4; pass++) {
    int i = pass * 64 + (t >> 2);
    int c = (t & 3) * 16;
    const uint4* p = (const uint4*)(Kb + (rowbase + i) * E_DIM + hoff + c);
    *(uint4*)&Ks[i][c] = p[0];
    *(uint4*)&Ks[i][c + 8] = p[1];
  }
#pragma unroll
  for (int rep = 0; rep < 8; rep++) {
    int u = rep * 256 + t;
    int i = u >> 3;
    int d0 = (u & 7) * 8;
    uint4 v = *(const uint4*)(Vb + (rowbase + i) * E_DIM + hoff + d0);
    const u16* pv = (const u16*)&v;
#pragma unroll
    for (int j = 0; j < 8; j++) Vt[d0 + j][i] = pv[j];
  }
  __syncthreads();

  for (int grp = 0; grp < 4; grp++) {
    {
      int i = t >> 2, c = (t & 3) * 16;
      const uint4* p = (const uint4*)(Qb + (rowbase + grp * 64 + i) * E_DIM + hoff + c);
      *(uint4*)&Qs[i][c] = p[0];
      *(uint4*)&Qs[i][c + 8] = p[1];
    }
    __syncthreads();

    bf16x8 qa0 = *(const bf16x8*)&Qs[wv * 16 + lr][g * 8];
    bf16x8 qa1 = *(const bf16x8*)&Qs[wv * 16 + lr][32 + g * 8];
    f4_t s[16];
#pragma unroll
    for (int ki = 0; ki < 16; ki++) {
      bf16x8 kb0 = *(const bf16x8*)&Ks[ki * 16 + lr][g * 8];
      bf16x8 kb1 = *(const bf16x8*)&Ks[ki * 16 + lr][32 + g * 8];
      f4_t z = {};
      z = mfma16(qa0, kb0, z);
      z = mfma16(qa1, kb1, z);
      s[ki] = z * 0.125f;
    }
    float m[4], sum[4];
#pragma unroll
    for (int r = 0; r < 4; r++) {
      float mx = -1e30f;
#pragma unroll
      for (int ki = 0; ki < 16; ki++) mx = fmaxf(mx, s[ki][r]);
      m[r] = mx;
    }
#pragma unroll
    for (int r = 0; r < 4; r++)
      for (int mask = 1; mask < 16; mask <<= 1) m[r] = fmaxf(m[r], __shfl_xor(m[r], mask));
#pragma unroll
    for (int r = 0; r < 4; r++) sum[r] = 0.f;
#pragma unroll
    for (int ki = 0; ki < 16; ki++) {
#pragma unroll
      for (int r = 0; r < 4; r++) {
        float p = __expf(s[ki][r] - m[r]);
        sum[r] += p;
        Ps[wv * 16 + g * 4 + r][ki * 16 + lr] = f2b(p);
      }
    }
#pragma unroll
    for (int r = 0; r < 4; r++)
      for (int mask = 1; mask < 16; mask <<= 1) sum[r] += __shfl_xor(sum[r], mask);
    if (lr == 0) {
#pragma unroll
      for (int r = 0; r < 4; r++) lsum[wv * 16 + g * 4 + r] = sum[r];
    }
    __syncthreads();

    f4_t o[4] = {};
#pragma unroll
    for (int kk = 0; kk < 8; kk++) {
      bf16x8 vb = *(const bf16x8*)&Vt[wv * 16 + lr][kk * 32 + g * 8];
#pragma unroll
      for (int mi = 0; mi < 4; mi++) {
        bf16x8 pa = *(const bf16x8*)&Ps[mi * 16 + lr][kk * 32 + g * 8];
        o[mi] = mfma16(pa, vb, o[mi]);
      }
    }
#pragma unroll
    for (int mi = 0; mi < 4; mi++) {
#pragma unroll
      for (int r = 0; r < 4; r++) {
        int qrow = mi * 16 + g * 4 + r;
        float val = o[mi][r] / lsum[qrow];
        size_t off = (((size_t)(b * NWIN + wdw) * 256 + grp * 64 + qrow) * E_DIM) + hoff + wv * 16 + lr;
        winctx[off] = f2b(val);
      }
    }
    __syncthreads();
  }
}

// ---------------- overlap-average combine: winctx -> ctxb rows 1..4096 ----------------
__global__ __launch_bounds__(256) void combine_kernel(const u16* __restrict__ winctx,
                                                      u16* __restrict__ ctxb) {
  int idx = blockIdx.x * 256 + threadIdx.x;
  int e0 = (idx & 127) * 8;
  int p = (idx >> 7) & 4095;
  int b = idx >> 19;
  int whi = p >> 7;
  if (whi > 30) whi = 30;
  int off_hi = p - whi * 128;
  int wlo = whi - 1;
  bool has_lo = (wlo >= 0) && (off_hi < 128);

  uint4 vhi = *(const uint4*)(winctx + (((size_t)(b * NWIN + whi) * 256 + off_hi) * E_DIM) + e0);
  const u16* ph = (const u16*)&vhi;
  float vals[8];
#pragma unroll
  for (int j = 0; j < 8; j++) vals[j] = b2f(ph[j]);
  if (has_lo) {
    uint4 vlo = *(const uint4*)(winctx + (((size_t)(b * NWIN + wlo) * 256 + off_hi + 128) * E_DIM) + e0);
    const u16* pl = (const u16*)&vlo;
#pragma unroll
    for (int j = 0; j < 8; j++) vals[j] = (vals[j] + b2f(pl[j])) * 0.5f;
  }
  u16 out[8];
#pragma unroll
  for (int j = 0; j < 8; j++) out[j] = f2b(vals[j]);
  *(uint4*)(ctxb + ((size_t)b * L_TOT + 1 + p) * E_DIM + e0) = *(uint4*)out;
}

// ---------------- launch ----------------
extern "C" void kernel_launch(void* const* d_in, const int* in_sizes, int n_in,
                              void* d_out, int out_size, void* d_ws, size_t ws_size,
                              hipStream_t stream) {
  const float* hs = (const float*)d_in[0];
  const float* Wq = (const float*)d_in[1];
  const float* bq = (const float*)d_in[2];
  const float* Wk = (const float*)d_in[3];
  const float* bk = (const float*)d_in[4];
  const float* Wv = (const float*)d_in[5];
  const float* bv = (const float*)d_in[6];
  const float* Wo = (const float*)d_in[7];
  const float* bo = (const float*)d_in[8];

  const size_t BLE = (size_t)M_ROWS * E_DIM;
  const size_t BLE_B = BLE * 2;
  const size_t EE = (size_t)E_DIM * E_DIM;

  char* ws = (char*)d_ws;
  u16* hsb = (u16*)(ws);
  u16* wtb = (u16*)(ws + BLE_B);                       // [4][1024][1024] = QKV concat + Wo
  u16* qkv = (u16*)(ws + BLE_B + 4 * EE * 2);
  u16* Qb = qkv;
  u16* Kb = qkv + BLE;
  u16* Vb = qkv + 2 * BLE;
  u16* ctxb = (u16*)(ws + BLE_B + 4 * EE * 2 + 3 * BLE_B);
  u16* winctx = (u16*)(ws + BLE_B + 4 * EE * 2 + 4 * BLE_B);
  float* gpart = (float*)(ws + BLE_B + 4 * EE * 2 + 4 * BLE_B +
                          (size_t)B_SZ * NWIN * 256 * E_DIM * 2);

  cvt_kernel<<<8194, 256, 0, stream>>>(hs, hsb, (int)(BLE / 4));
  wtrans_kernel<<<dim3(32, 32, 4), dim3(32, 8), 0, stream>>>(Wq, Wk, Wv, Wo, wtb);
  // QKV fused: N = 3072 -> 33 m-tiles x 12 n-tiles = 396 blocks
  gemm8_kernel<0><<<33 * 12, 512, 0, stream>>>(hsb, wtb, bq, bk, bv, qkv, M_ROWS, 12);
  gattn1_kernel<<<dim3(GCHUNKS, HHEADS, B_SZ), 256, 0, stream>>>(Qb, Kb, Vb, gpart);
  gattn2_kernel<<<32, 64, 0, stream>>>(gpart, ctxb);
  wattn_kernel<<<dim3(NWIN, HHEADS, B_SZ), 256, 0, stream>>>(Qb, Kb, Vb, winctx);
  combine_kernel<<<4096, 256, 0, stream>>>(winctx, ctxb);
  // output projection: N = 1024 -> 33 x 4 = 132 blocks
  gemm8_kernel<1><<<33 * 4, 512, 0, stream>>>(ctxb, wtb + 3 * EE, bo, bo, bo, d_out, M_ROWS, 4);
}

// Round 5
// 281.346 us; speedup vs baseline: 1.0083x; 1.0083x over previous
//
#include <hip/hip_runtime.h>

typedef unsigned short u16;
typedef unsigned int u32;
typedef __bf16 bf16x8 __attribute__((ext_vector_type(8)));
typedef float f4_t __attribute__((ext_vector_type(4)));

#define E_DIM 1024
#define L_TOT 4097
#define B_SZ 2
#define M_ROWS 8194   // B*L
#define NWIN 31
#define HHEADS 16
#define GCHUNKS 17    // ceil(4097/256)

__device__ __forceinline__ float b2f(u16 v) {
  union { u32 u; float f; } x; x.u = ((u32)v) << 16; return x.f;
}
__device__ __forceinline__ u16 f2b(float f) {
  union { float f; u32 u; } x; x.f = f;
  u32 r = (x.u + 0x7FFFu + ((x.u >> 16) & 1u)) >> 16;
  return (u16)r;
}
__device__ __forceinline__ f4_t mfma16(bf16x8 a, bf16x8 b, f4_t c) {
  return __builtin_amdgcn_mfma_f32_16x16x32_bf16(a, b, c, 0, 0, 0);
}

// async global->LDS, 16B per lane; LDS dest = wave-uniform base + lane*16
#define GLOAD16(gp, lp)                                                              \
  __builtin_amdgcn_global_load_lds(                                                  \
      (const __attribute__((address_space(1))) u32*)(gp),                            \
      (__attribute__((address_space(3))) u32*)(lp), 16, 0, 0)

// ---------------- fp32 -> bf16 convert (hidden states) ----------------
__global__ __launch_bounds__(256) void cvt_kernel(const float* __restrict__ src,
                                                  u16* __restrict__ dst, int n4) {
  int i = blockIdx.x * 256 + threadIdx.x;
  if (i >= n4) return;
  float4 v = ((const float4*)src)[i];
  u16 o[4] = {f2b(v.x), f2b(v.y), f2b(v.z), f2b(v.w)};
  *(uint2*)(dst + (size_t)i * 4) = *(uint2*)o;
}

// ---------------- weight transpose + convert: W (K x N) -> Wt (N x K) bf16 ----------------
__global__ __launch_bounds__(256) void wtrans_kernel(const float* __restrict__ w0,
                                                     const float* __restrict__ w1,
                                                     const float* __restrict__ w2,
                                                     const float* __restrict__ w3,
                                                     u16* __restrict__ wtb) {
  const float* src = blockIdx.z == 0 ? w0 : blockIdx.z == 1 ? w1 : blockIdx.z == 2 ? w2 : w3;
  u16* dst = wtb + (size_t)blockIdx.z * E_DIM * E_DIM;
  __shared__ float tile[32][33];
  int tx = threadIdx.x, ty = threadIdx.y;
  int x = blockIdx.x * 32 + tx;
  int y0 = blockIdx.y * 32;
  for (int j = ty; j < 32; j += 8) tile[j][tx] = src[(size_t)(y0 + j) * E_DIM + x];
  __syncthreads();
  for (int j = ty; j < 32; j += 8)
    dst[(size_t)(blockIdx.x * 32 + j) * E_DIM + blockIdx.y * 32 + tx] = f2b(tile[tx][j]);
}

// ================= GEMM: 128x128 tile, BK=64, 2-phase, 256 thr, 3-4 blocks/CU =======
// C(M x NTIL*128) = A(M x 1024) * Wt^T + bias; Wt stored [N][1024].
// LDS staging linear [128][64] per operand with XOR swizzle slot^=(row&7):
// linear DMA dest, inverse-swizzled global source col, swizzled ds_read (verified r4: 0 conflicts).
// Epilogue: acc -> LDS -> full-line coalesced stores.
// MODE 0: bf16 demux to 3 tensors [M_ROWS][1024]. MODE 1: fp32 single tensor.
template <int MODE>
__global__ __launch_bounds__(256) void gemmA_kernel(const u16* __restrict__ A,
                                                    const u16* __restrict__ Wt,
                                                    const float* __restrict__ b0,
                                                    const float* __restrict__ b1,
                                                    const float* __restrict__ b2,
                                                    void* __restrict__ outBase,
                                                    int M, int NTIL) {
  __shared__ __align__(16) char smraw[34816];
  u16* sA = (u16*)smraw;            // [128][64] u16 = 16 KB
  u16* sB = sA + 128 * 64;          // 16 KB
  u16* epi16 = (u16*)smraw;         // [128][136] u16 (MODE 0 epilogue)
  float* epi32 = (float*)smraw;     // [128][68] f32 (MODE 1 epilogue)

  // bijective XCD swizzle, nt-fast within each XCD chunk
  int nwg = gridDim.x;
  int q8 = nwg >> 3, r8 = nwg & 7;
  int orig = blockIdx.x;
  int xcd = orig & 7, loc = orig >> 3;
  int wg = (xcd < r8 ? xcd * (q8 + 1) : r8 * (q8 + 1) + (xcd - r8) * q8) + loc;
  int mt = wg / NTIL, nt = wg - mt * NTIL;
  int m0 = mt * 128, n0 = nt * 128;

  int t = threadIdx.x, lane = t & 63, w = t >> 6;
  int wr = w >> 1, wc = w & 1;
  int lr = lane & 15, g = lane >> 4;

  // staging: thread t covers row (c*32 + (t>>3)), phys slot (t&7); source slot inverse-swizzled
  int rsub = t >> 3;                          // 0..31
  int ssrc = ((t & 7) ^ (rsub & 7)) * 8;      // element offset in row
  int wbase = w * 512;                        // u16; + lane*8 u16 = lane*16 B (wave-contiguous 1KB)
  const u16* pa[4];
  const u16* pb[4];
#pragma unroll
  for (int c = 0; c < 4; c++) {
    int ra = m0 + c * 32 + rsub;
    if (ra >= M) ra = M - 1;
    pa[c] = A + (size_t)ra * 1024 + ssrc;
    pb[c] = Wt + (size_t)(n0 + c * 32 + rsub) * 1024 + ssrc;
  }

  f4_t acc[4][4] = {};

  for (int kt = 0; kt < 16; ++kt) {
    int ko = kt * 64;
#pragma unroll
    for (int c = 0; c < 4; c++) {
      GLOAD16(pa[c] + ko, sA + c * 2048 + wbase);
      GLOAD16(pb[c] + ko, sB + c * 2048 + wbase);
    }
    __syncthreads();  // compiler drains vmcnt(0) -> staged data visible
#pragma unroll
    for (int kk = 0; kk < 2; kk++) {
      int sl = ((kk * 4 + g) ^ (lr & 7)) * 8;
      bf16x8 av[4], bv[4];
#pragma unroll
      for (int i = 0; i < 4; i++) av[i] = *(const bf16x8*)&sA[(wr * 64 + i * 16 + lr) * 64 + sl];
#pragma unroll
      for (int j = 0; j < 4; j++) bv[j] = *(const bf16x8*)&sB[(wc * 64 + j * 16 + lr) * 64 + sl];
#pragma unroll
      for (int i = 0; i < 4; i++)
#pragma unroll
        for (int j = 0; j < 4; j++) acc[i][j] = mfma16(av[i], bv[j], acc[i][j]);
    }
    __syncthreads();  // all reads done before next stage overwrites
  }

  // ---------------- coalesced epilogue via LDS ----------------
  if (MODE == 0) {
    int tsel = n0 >> 10, ncb = n0 & 1023;
    const float* bp = tsel == 0 ? b0 : (tsel == 1 ? b1 : b2);
#pragma unroll
    for (int j = 0; j < 4; j++) {
      int ncl = wc * 64 + j * 16 + lr;
      float bb = bp[ncb + ncl];
#pragma unroll
      for (int i = 0; i < 4; i++) {
        int mlb = wr * 64 + i * 16 + g * 4;
#pragma unroll
        for (int r = 0; r < 4; r++) epi16[(mlb + r) * 136 + ncl] = f2b(acc[i][j][r] + bb);
      }
    }
    __syncthreads();
    int row = t >> 1, half = t & 1;
    int m = m0 + row;
    if (m < M) {
      u16* op = (u16*)outBase + (size_t)tsel * ((size_t)M_ROWS * E_DIM) + (size_t)m * E_DIM + ncb + half * 64;
      const u16* lp = epi16 + row * 136 + half * 64;
#pragma unroll
      for (int qd = 0; qd < 8; qd++) ((uint4*)op)[qd] = ((const uint4*)lp)[qd];
    }
  } else {
#pragma unroll
    for (int p = 0; p < 2; p++) {
      if (p) __syncthreads();
      if (wc == p) {
#pragma unroll
        for (int j = 0; j < 4; j++) {
          int ncl = j * 16 + lr;
          float bb = b0[n0 + p * 64 + ncl];
#pragma unroll
          for (int i = 0; i < 4; i++) {
            int mlb = wr * 64 + i * 16 + g * 4;
#pragma unroll
            for (int r = 0; r < 4; r++) epi32[(mlb + r) * 68 + ncl] = acc[i][j][r] + bb;
          }
        }
      }
      __syncthreads();
      int row = t >> 1, qr = t & 1;
      int m = m0 + row;
      if (m < M) {
        float* op = (float*)outBase + (size_t)m * E_DIM + n0 + p * 64 + qr * 32;
        const float* lp = epi32 + row * 68 + qr * 32;
#pragma unroll
        for (int qd = 0; qd < 8; qd++) ((float4*)op)[qd] = ((const float4*)lp)[qd];
      }
    }
  }
}

// ---------------- global attention, phase 1: per-chunk partials ----------------
__global__ __launch_bounds__(256) void gattn1_kernel(const u16* __restrict__ Qb,
                                                     const u16* __restrict__ Kb,
                                                     const u16* __restrict__ Vb,
                                                     float* __restrict__ part) {
  int c = blockIdx.x;
  int h = blockIdx.y;
  int b = blockIdx.z;
  int t = threadIdx.x;
  __shared__ float qsh[64];
  __shared__ float red[4];
  __shared__ float psh[256];
  __shared__ float cred[4][64];

  size_t base = (size_t)b * L_TOT * E_DIM + h * 64;
  if (t < 64) qsh[t] = b2f(Qb[base + t]);
  __syncthreads();

  int row = c * 256 + t;
  bool valid = row < L_TOT;
  float dot = -1e30f;
  if (valid) {
    const u16* kp = Kb + base + (size_t)row * E_DIM;
    float acc = 0.f;
#pragma unroll
    for (int j = 0; j < 64; j += 8) {
      uint4 kv = *(const uint4*)(kp + j);
      const u16* kk = (const u16*)&kv;
#pragma unroll
      for (int q = 0; q < 8; q++) acc += qsh[j + q] * b2f(kk[q]);
    }
    dot = acc * 0.125f;
  }
  float m = dot;
  for (int mask = 1; mask < 64; mask <<= 1) m = fmaxf(m, __shfl_xor(m, mask));
  if ((t & 63) == 0) red[t >> 6] = m;
  __syncthreads();
  m = fmaxf(fmaxf(red[0], red[1]), fmaxf(red[2], red[3]));
  float p = valid ? __expf(dot - m) : 0.f;
  psh[t] = p;
  float s = p;
  for (int mask = 1; mask < 64; mask <<= 1) s += __shfl_xor(s, mask);
  __syncthreads();
  if ((t & 63) == 0) red[t >> 6] = s;
  __syncthreads();
  s = red[0] + red[1] + red[2] + red[3];

  int d = t & 63, gq = t >> 6;
  float acc = 0.f;
#pragma unroll 4
  for (int i = 0; i < 64; i++) {
    int sl = gq * 64 + i;
    int r2 = c * 256 + sl;
    if (r2 < L_TOT) acc += psh[sl] * b2f(Vb[base + (size_t)r2 * E_DIM + d]);
  }
  cred[gq][d] = acc;
  __syncthreads();
  if (t < 64) {
    float v = cred[0][t] + cred[1][t] + cred[2][t] + cred[3][t];
    float* pp = part + (((size_t)(b * HHEADS + h) * GCHUNKS + c) * 66);
    pp[t] = v;
    if (t == 0) { pp[64] = m; pp[65] = s; }
  }
}

// ---------------- global attention, phase 2: combine chunks ----------------
__global__ __launch_bounds__(64) void gattn2_kernel(const float* __restrict__ part,
                                                    u16* __restrict__ ctxb) {
  int bh = blockIdx.x;
  int b = bh >> 4, h = bh & 15;
  int d = threadIdx.x;
  const float* pp = part + ((size_t)(b * HHEADS + h) * GCHUNKS) * 66;
  float m = -1e30f;
#pragma unroll
  for (int c = 0; c < GCHUNKS; c++) m = fmaxf(m, pp[c * 66 + 64]);
  float stot = 0.f, acc = 0.f;
#pragma unroll
  for (int c = 0; c < GCHUNKS; c++) {
    float w = __expf(pp[c * 66 + 64] - m);
    stot += pp[c * 66 + 65] * w;
    acc += pp[c * 66 + d] * w;
  }
  ctxb[(size_t)b * L_TOT * E_DIM + h * 64 + d] = f2b(acc / stot);
}

// ---------------- windowed attention: one block per (w, h, b) ----------------
__global__ __launch_bounds__(256) void wattn_kernel(const u16* __restrict__ Qb,
                                                    const u16* __restrict__ Kb,
                                                    const u16* __restrict__ Vb,
                                                    u16* __restrict__ winctx) {
  int wdw = blockIdx.x;
  int h = blockIdx.y;
  int b = blockIdx.z;

  __shared__ u16 Ks[256][72];
  __shared__ u16 Vt[64][264];
  __shared__ u16 Ps[64][264];
  __shared__ u16 Qs[64][72];
  __shared__ float lsum[64];

  int t = threadIdx.x, lane = t & 63, wv = t >> 6;
  int g = lane >> 4, lr = lane & 15;
  size_t rowbase = (size_t)b * L_TOT + 1 + (size_t)wdw * 128;
  int hoff = h * 64;

#pragma unroll
  for (int pass = 0; pass < 4; pass++) {
    int i = pass * 64 + (t >> 2);
    int c = (t & 3) * 16;
    const uint4* p = (const uint4*)(Kb + (rowbase + i) * E_DIM + hoff + c);
    *(uint4*)&Ks[i][c] = p[0];
    *(uint4*)&Ks[i][c + 8] = p[1];
  }
#pragma unroll
  for (int rep = 0; rep < 8; rep++) {
    int u = rep * 256 + t;
    int i = u >> 3;
    int d0 = (u & 7) * 8;
    uint4 v = *(const uint4*)(Vb + (rowbase + i) * E_DIM + hoff + d0);
    const u16* pv = (const u16*)&v;
#pragma unroll
    for (int j = 0; j < 8; j++) Vt[d0 + j][i] = pv[j];
  }
  __syncthreads();

  for (int grp = 0; grp < 4; grp++) {
    {
      int i = t >> 2, c = (t & 3) * 16;
      const uint4* p = (const uint4*)(Qb + (rowbase + grp * 64 + i) * E_DIM + hoff + c);
      *(uint4*)&Qs[i][c] = p[0];
      *(uint4*)&Qs[i][c + 8] = p[1];
    }
    __syncthreads();

    bf16x8 qa0 = *(const bf16x8*)&Qs[wv * 16 + lr][g * 8];
    bf16x8 qa1 = *(const bf16x8*)&Qs[wv * 16 + lr][32 + g * 8];
    f4_t s[16];
#pragma unroll
    for (int ki = 0; ki < 16; ki++) {
      bf16x8 kb0 = *(const bf16x8*)&Ks[ki * 16 + lr][g * 8];
      bf16x8 kb1 = *(const bf16x8*)&Ks[ki * 16 + lr][32 + g * 8];
      f4_t z = {};
      z = mfma16(qa0, kb0, z);
      z = mfma16(qa1, kb1, z);
      s[ki] = z * 0.125f;
    }
    float m[4], sum[4];
#pragma unroll
    for (int r = 0; r < 4; r++) {
      float mx = -1e30f;
#pragma unroll
      for (int ki = 0; ki < 16; ki++) mx = fmaxf(mx, s[ki][r]);
      m[r] = mx;
    }
#pragma unroll
    for (int r = 0; r < 4; r++)
      for (int mask = 1; mask < 16; mask <<= 1) m[r] = fmaxf(m[r], __shfl_xor(m[r], mask));
#pragma unroll
    for (int r = 0; r < 4; r++) sum[r] = 0.f;
#pragma unroll
    for (int ki = 0; ki < 16; ki++) {
#pragma unroll
      for (int r = 0; r < 4; r++) {
        float p = __expf(s[ki][r] - m[r]);
        sum[r] += p;
        Ps[wv * 16 + g * 4 + r][ki * 16 + lr] = f2b(p);
      }
    }
#pragma unroll
    for (int r = 0; r < 4; r++)
      for (int mask = 1; mask < 16; mask <<= 1) sum[r] += __shfl_xor(sum[r], mask);
    if (lr == 0) {
#pragma unroll
      for (int r = 0; r < 4; r++) lsum[wv * 16 + g * 4 + r] = sum[r];
    }
    __syncthreads();

    f4_t o[4] = {};
#pragma unroll
    for (int kk = 0; kk < 8; kk++) {
      bf16x8 vb = *(const bf16x8*)&Vt[wv * 16 + lr][kk * 32 + g * 8];
#pragma unroll
      for (int mi = 0; mi < 4; mi++) {
        bf16x8 pa = *(const bf16x8*)&Ps[mi * 16 + lr][kk * 32 + g * 8];
        o[mi] = mfma16(pa, vb, o[mi]);
      }
    }
#pragma unroll
    for (int mi = 0; mi < 4; mi++) {
#pragma unroll
      for (int r = 0; r < 4; r++) {
        int qrow = mi * 16 + g * 4 + r;
        float val = o[mi][r] / lsum[qrow];
        size_t off = (((size_t)(b * NWIN + wdw) * 256 + grp * 64 + qrow) * E_DIM) + hoff + wv * 16 + lr;
        winctx[off] = f2b(val);
      }
    }
    __syncthreads();
  }
}

// ---------------- overlap-average combine: winctx -> ctxb rows 1..4096 ----------------
__global__ __launch_bounds__(256) void combine_kernel(const u16* __restrict__ winctx,
                                                      u16* __restrict__ ctxb) {
  int idx = blockIdx.x * 256 + threadIdx.x;
  int e0 = (idx & 127) * 8;
  int p = (idx >> 7) & 4095;
  int b = idx >> 19;
  int whi = p >> 7;
  if (whi > 30) whi = 30;
  int off_hi = p - whi * 128;
  int wlo = whi - 1;
  bool has_lo = (wlo >= 0) && (off_hi < 128);

  uint4 vhi = *(const uint4*)(winctx + (((size_t)(b * NWIN + whi) * 256 + off_hi) * E_DIM) + e0);
  const u16* ph = (const u16*)&vhi;
  float vals[8];
#pragma unroll
  for (int j = 0; j < 8; j++) vals[j] = b2f(ph[j]);
  if (has_lo) {
    uint4 vlo = *(const uint4*)(winctx + (((size_t)(b * NWIN + wlo) * 256 + off_hi + 128) * E_DIM) + e0);
    const u16* pl = (const u16*)&vlo;
#pragma unroll
    for (int j = 0; j < 8; j++) vals[j] = (vals[j] + b2f(pl[j])) * 0.5f;
  }
  u16 out[8];
#pragma unroll
  for (int j = 0; j < 8; j++) out[j] = f2b(vals[j]);
  *(uint4*)(ctxb + ((size_t)b * L_TOT + 1 + p) * E_DIM + e0) = *(uint4*)out;
}

// ---------------- launch ----------------
extern "C" void kernel_launch(void* const* d_in, const int* in_sizes, int n_in,
                              void* d_out, int out_size, void* d_ws, size_t ws_size,
                              hipStream_t stream) {
  const float* hs = (const float*)d_in[0];
  const float* Wq = (const float*)d_in[1];
  const float* bq = (const float*)d_in[2];
  const float* Wk = (const float*)d_in[3];
  const float* bk = (const float*)d_in[4];
  const float* Wv = (const float*)d_in[5];
  const float* bv = (const float*)d_in[6];
  const float* Wo = (const float*)d_in[7];
  const float* bo = (const float*)d_in[8];

  const size_t BLE = (size_t)M_ROWS * E_DIM;
  const size_t BLE_B = BLE * 2;
  const size_t EE = (size_t)E_DIM * E_DIM;

  char* ws = (char*)d_ws;
  u16* hsb = (u16*)(ws);
  u16* wtb = (u16*)(ws + BLE_B);                       // [4][1024][1024] = QKV concat + Wo
  u16* qkv = (u16*)(ws + BLE_B + 4 * EE * 2);
  u16* Qb = qkv;
  u16* Kb = qkv + BLE;
  u16* Vb = qkv + 2 * BLE;
  u16* ctxb = (u16*)(ws + BLE_B + 4 * EE * 2 + 3 * BLE_B);
  u16* winctx = (u16*)(ws + BLE_B + 4 * EE * 2 + 4 * BLE_B);
  float* gpart = (float*)(ws + BLE_B + 4 * EE * 2 + 4 * BLE_B +
                          (size_t)B_SZ * NWIN * 256 * E_DIM * 2);

  cvt_kernel<<<8194, 256, 0, stream>>>(hs, hsb, (int)(BLE / 4));
  wtrans_kernel<<<dim3(32, 32, 4), dim3(32, 8), 0, stream>>>(Wq, Wk, Wv, Wo, wtb);
  // QKV fused: N = 3072 -> 65 m-tiles x 24 n-tiles = 1560 blocks
  gemmA_kernel<0><<<65 * 24, 256, 0, stream>>>(hsb, wtb, bq, bk, bv, qkv, M_ROWS, 24);
  gattn1_kernel<<<dim3(GCHUNKS, HHEADS, B_SZ), 256, 0, stream>>>(Qb, Kb, Vb, gpart);
  gattn2_kernel<<<32, 64, 0, stream>>>(gpart, ctxb);
  wattn_kernel<<<dim3(NWIN, HHEADS, B_SZ), 256, 0, stream>>>(Qb, Kb, Vb, winctx);
  combine_kernel<<<4096, 256, 0, stream>>>(winctx, ctxb);
  // output projection: N = 1024 -> 65 x 8 = 520 blocks
  gemmA_kernel<1><<<65 * 8, 256, 0, stream>>>(ctxb, wtb + 3 * EE, bo, bo, bo, d_out, M_ROWS, 8);
}

// Round 6
// 260.606 us; speedup vs baseline: 1.0885x; 1.0796x over previous
//
#include <hip/hip_runtime.h>

typedef unsigned short u16;
typedef unsigned int u32;
typedef __bf16 bf16x8 __attribute__((ext_vector_type(8)));
typedef float f4_t __attribute__((ext_vector_type(4)));

#define E_DIM 1024
#define L_TOT 4097
#define B_SZ 2
#define M_ROWS 8194   // B*L
#define NWIN 31
#define HHEADS 16
#define GCHUNKS 17    // ceil(4097/256)

__device__ __forceinline__ float b2f(u16 v) {
  union { u32 u; float f; } x; x.u = ((u32)v) << 16; return x.f;
}
__device__ __forceinline__ u16 f2b(float f) {
  union { float f; u32 u; } x; x.f = f;
  u32 r = (x.u + 0x7FFFu + ((x.u >> 16) & 1u)) >> 16;
  return (u16)r;
}
__device__ __forceinline__ f4_t mfma16(bf16x8 a, bf16x8 b, f4_t c) {
  return __builtin_amdgcn_mfma_f32_16x16x32_bf16(a, b, c, 0, 0, 0);
}

// async global->LDS, 16B per lane; LDS dest = wave-uniform base + lane*16
#define GLOAD16(gp, lp)                                                              \
  __builtin_amdgcn_global_load_lds(                                                  \
      (const __attribute__((address_space(1))) u32*)(gp),                            \
      (__attribute__((address_space(3))) u32*)(lp), 16, 0, 0)

// ---------------- fp32 -> bf16 convert (hidden states) ----------------
__global__ __launch_bounds__(256) void cvt_kernel(const float* __restrict__ src,
                                                  u16* __restrict__ dst, int n4) {
  int i = blockIdx.x * 256 + threadIdx.x;
  if (i >= n4) return;
  float4 v = ((const float4*)src)[i];
  u16 o[4] = {f2b(v.x), f2b(v.y), f2b(v.z), f2b(v.w)};
  *(uint2*)(dst + (size_t)i * 4) = *(uint2*)o;
}

// ---------------- weight transpose + convert: W (K x N) -> Wt (N x K) bf16 ----------------
__global__ __launch_bounds__(256) void wtrans_kernel(const float* __restrict__ w0,
                                                     const float* __restrict__ w1,
                                                     const float* __restrict__ w2,
                                                     const float* __restrict__ w3,
                                                     u16* __restrict__ wtb) {
  const float* src = blockIdx.z == 0 ? w0 : blockIdx.z == 1 ? w1 : blockIdx.z == 2 ? w2 : w3;
  u16* dst = wtb + (size_t)blockIdx.z * E_DIM * E_DIM;
  __shared__ float tile[32][33];
  int tx = threadIdx.x, ty = threadIdx.y;
  int x = blockIdx.x * 32 + tx;
  int y0 = blockIdx.y * 32;
  for (int j = ty; j < 32; j += 8) tile[j][tx] = src[(size_t)(y0 + j) * E_DIM + x];
  __syncthreads();
  for (int j = ty; j < 32; j += 8)
    dst[(size_t)(blockIdx.x * 32 + j) * E_DIM + blockIdx.y * 32 + tx] = f2b(tile[tx][j]);
}

// ================= GEMM: 128 x BN tile, BK=64, DOUBLE-BUFFERED, 256 thr ==========
// C(M x NTIL*BN) = A(M x 1024) * Wt^T + bias; Wt stored [N][1024].
// Key change vs r5: stage(t+1) issued BEFORE compute(t); ONE barrier per K-iter.
// A buffer is overwritten a full iteration after its last ds_read (lgkmcnt waits
// precede the MFMAs which precede the barrier) -> race-free with 2 buffers.
// LDS swizzle as r4/r5 (verified 0 conflicts): linear DMA dest, inverse-swizzled
// global source slot, swizzled ds_read slot.
// MODE 0 (BN=128): bf16 demux to 3 tensors [M_ROWS][1024]. MODE 1 (BN=64): fp32.
template <int MODE, int BN>
__global__ __launch_bounds__(256) void gemmB_kernel(const u16* __restrict__ A,
                                                    const u16* __restrict__ Wt,
                                                    const float* __restrict__ b0,
                                                    const float* __restrict__ b1,
                                                    const float* __restrict__ b2,
                                                    void* __restrict__ outBase,
                                                    int M, int NTIL) {
  constexpr int NB = BN / 32;       // B staging rounds; also acc cols per wave
  constexpr int ABUF = 128 * 64;    // u16 per A buffer
  constexpr int BBUF = BN * 64;     // u16 per B buffer
  __shared__ __align__(16) u16 sm[2 * ABUF + 2 * BBUF];
  u16* sA = sm;                     // [2][128][64]
  u16* sB = sm + 2 * ABUF;          // [2][BN][64]
  u16* epi16 = sm;                  // [128][136] (MODE 0 epilogue, aliases)
  float* epi32 = (float*)sm;        // [128][68]  (MODE 1 epilogue, aliases)

  // bijective XCD swizzle, nt-fast within each XCD chunk (A-panel L2 reuse)
  int nwg = gridDim.x;
  int q8 = nwg >> 3, r8 = nwg & 7;
  int orig = blockIdx.x;
  int xcd = orig & 7, loc = orig >> 3;
  int wg = (xcd < r8 ? xcd * (q8 + 1) : r8 * (q8 + 1) + (xcd - r8) * q8) + loc;
  int mt = wg / NTIL, nt = wg - mt * NTIL;
  int m0 = mt * 128, n0 = nt * BN;

  int t = threadIdx.x, lane = t & 63, w = t >> 6;
  int wr = w >> 1, wc = w & 1;
  int lr = lane & 15, g = lane >> 4;

  // staging: thread t covers row (round*32 + (t>>3)), phys slot (t&7);
  // global source slot inverse-swizzled so read-side XOR lands on the right data
  int rsub = t >> 3;
  int ssrc = ((t & 7) ^ (rsub & 7)) * 8;
  int wbase = w * 512;  // u16; +lane*8 u16 = lane*16B, wave-contiguous 1KB
  const u16* pa[4];
  const u16* pb[NB];
#pragma unroll
  for (int c = 0; c < 4; c++) {
    int ra = m0 + c * 32 + rsub;
    if (ra >= M) ra = M - 1;
    pa[c] = A + (size_t)ra * 1024 + ssrc;
  }
#pragma unroll
  for (int c = 0; c < NB; c++) pb[c] = Wt + (size_t)(n0 + c * 32 + rsub) * 1024 + ssrc;

#define STAGE(bf, kt)                                                      \
  {                                                                        \
    int ko_ = (kt) * 64;                                                   \
    _Pragma("unroll") for (int c_ = 0; c_ < 4; c_++)                       \
        GLOAD16(pa[c_] + ko_, sA + (bf) * ABUF + c_ * 2048 + wbase);       \
    _Pragma("unroll") for (int c_ = 0; c_ < NB; c_++)                      \
        GLOAD16(pb[c_] + ko_, sB + (bf) * BBUF + c_ * 2048 + wbase);       \
  }

#define COMPUTE(bf)                                                            \
  {                                                                            \
    _Pragma("unroll") for (int kk_ = 0; kk_ < 2; kk_++) {                      \
      int sl_ = ((kk_ * 4 + g) ^ (lr & 7)) * 8;                                \
      bf16x8 av_[4], bv_[NB];                                                  \
      _Pragma("unroll") for (int i_ = 0; i_ < 4; i_++)                         \
          av_[i_] = *(const bf16x8*)&sA[(bf) * ABUF + (wr * 64 + i_ * 16 + lr) * 64 + sl_]; \
      _Pragma("unroll") for (int j_ = 0; j_ < NB; j_++)                        \
          bv_[j_] = *(const bf16x8*)&sB[(bf) * BBUF + (wc * (BN / 2) + j_ * 16 + lr) * 64 + sl_]; \
      _Pragma("unroll") for (int i_ = 0; i_ < 4; i_++)                         \
        _Pragma("unroll") for (int j_ = 0; j_ < NB; j_++)                      \
            acc[i_][j_] = mfma16(av_[i_], bv_[j_], acc[i_][j_]);               \
    }                                                                          \
  }

  f4_t acc[4][NB] = {};

  // prologue: stage tile 0, drain, barrier
  STAGE(0, 0);
  __syncthreads();

  int buf = 0;
  for (int kt = 0; kt < 15; ++kt) {
    STAGE(buf ^ 1, kt + 1);                 // issue next-tile loads FIRST
    __builtin_amdgcn_sched_barrier(0);      // pin issue before compute
    COMPUTE(buf);                           // ds_read + MFMA hide the HBM latency
    __syncthreads();                        // drains vmcnt(0): next tile landed
    buf ^= 1;
  }
  COMPUTE(buf);
  __syncthreads();  // protect LDS before epilogue aliasing

  // ---------------- coalesced epilogue via LDS ----------------
  if (MODE == 0) {
    int tsel = n0 >> 10, ncb = n0 & 1023;
    const float* bp = tsel == 0 ? b0 : (tsel == 1 ? b1 : b2);
#pragma unroll
    for (int j = 0; j < NB; j++) {
      int ncl = wc * (BN / 2) + j * 16 + lr;
      float bb = bp[ncb + ncl];
#pragma unroll
      for (int i = 0; i < 4; i++) {
        int mlb = wr * 64 + i * 16 + g * 4;
#pragma unroll
        for (int r = 0; r < 4; r++) epi16[(mlb + r) * 136 + ncl] = f2b(acc[i][j][r] + bb);
      }
    }
    __syncthreads();
    int row = t >> 1, half = t & 1;
    int m = m0 + row;
    if (m < M) {
      u16* op = (u16*)outBase + (size_t)tsel * ((size_t)M_ROWS * E_DIM) + (size_t)m * E_DIM + ncb + half * 64;
      const u16* lp = epi16 + row * 136 + half * 64;
#pragma unroll
      for (int qd = 0; qd < 8; qd++) ((uint4*)op)[qd] = ((const uint4*)lp)[qd];
    }
  } else {
    // BN = 64: single pass, all 128 rows x 64 cols fp32
#pragma unroll
    for (int j = 0; j < NB; j++) {
      int ncl = wc * (BN / 2) + j * 16 + lr;
      float bb = b0[n0 + ncl];
#pragma unroll
      for (int i = 0; i < 4; i++) {
        int mlb = wr * 64 + i * 16 + g * 4;
#pragma unroll
        for (int r = 0; r < 4; r++) epi32[(mlb + r) * 68 + ncl] = acc[i][j][r] + bb;
      }
    }
    __syncthreads();
    int row = t >> 1, half = t & 1;
    int m = m0 + row;
    if (m < M) {
      float* op = (float*)outBase + (size_t)m * E_DIM + n0 + half * 32;
      const float* lp = epi32 + row * 68 + half * 32;
#pragma unroll
      for (int qd = 0; qd < 8; qd++) ((float4*)op)[qd] = ((const float4*)lp)[qd];
    }
  }
#undef STAGE
#undef COMPUTE
}

// ---------------- global attention, phase 1: per-chunk partials ----------------
__global__ __launch_bounds__(256) void gattn1_kernel(const u16* __restrict__ Qb,
                                                     const u16* __restrict__ Kb,
                                                     const u16* __restrict__ Vb,
                                                     float* __restrict__ part) {
  int c = blockIdx.x;
  int h = blockIdx.y;
  int b = blockIdx.z;
  int t = threadIdx.x;
  __shared__ float qsh[64];
  __shared__ float red[4];
  __shared__ float psh[256];
  __shared__ float cred[4][64];

  size_t base = (size_t)b * L_TOT * E_DIM + h * 64;
  if (t < 64) qsh[t] = b2f(Qb[base + t]);
  __syncthreads();

  int row = c * 256 + t;
  bool valid = row < L_TOT;
  float dot = -1e30f;
  if (valid) {
    const u16* kp = Kb + base + (size_t)row * E_DIM;
    float acc = 0.f;
#pragma unroll
    for (int j = 0; j < 64; j += 8) {
      uint4 kv = *(const uint4*)(kp + j);
      const u16* kk = (const u16*)&kv;
#pragma unroll
      for (int q = 0; q < 8; q++) acc += qsh[j + q] * b2f(kk[q]);
    }
    dot = acc * 0.125f;
  }
  float m = dot;
  for (int mask = 1; mask < 64; mask <<= 1) m = fmaxf(m, __shfl_xor(m, mask));
  if ((t & 63) == 0) red[t >> 6] = m;
  __syncthreads();
  m = fmaxf(fmaxf(red[0], red[1]), fmaxf(red[2], red[3]));
  float p = valid ? __expf(dot - m) : 0.f;
  psh[t] = p;
  float s = p;
  for (int mask = 1; mask < 64; mask <<= 1) s += __shfl_xor(s, mask);
  __syncthreads();
  if ((t & 63) == 0) red[t >> 6] = s;
  __syncthreads();
  s = red[0] + red[1] + red[2] + red[3];

  int d = t & 63, gq = t >> 6;
  float acc = 0.f;
#pragma unroll 4
  for (int i = 0; i < 64; i++) {
    int sl = gq * 64 + i;
    int r2 = c * 256 + sl;
    if (r2 < L_TOT) acc += psh[sl] * b2f(Vb[base + (size_t)r2 * E_DIM + d]);
  }
  cred[gq][d] = acc;
  __syncthreads();
  if (t < 64) {
    float v = cred[0][t] + cred[1][t] + cred[2][t] + cred[3][t];
    float* pp = part + (((size_t)(b * HHEADS + h) * GCHUNKS + c) * 66);
    pp[t] = v;
    if (t == 0) { pp[64] = m; pp[65] = s; }
  }
}

// ---------------- global attention, phase 2: combine chunks ----------------
__global__ __launch_bounds__(64) void gattn2_kernel(const float* __restrict__ part,
                                                    u16* __restrict__ ctxb) {
  int bh = blockIdx.x;
  int b = bh >> 4, h = bh & 15;
  int d = threadIdx.x;
  const float* pp = part + ((size_t)(b * HHEADS + h) * GCHUNKS) * 66;
  float m = -1e30f;
#pragma unroll
  for (int c = 0; c < GCHUNKS; c++) m = fmaxf(m, pp[c * 66 + 64]);
  float stot = 0.f, acc = 0.f;
#pragma unroll
  for (int c = 0; c < GCHUNKS; c++) {
    float w = __expf(pp[c * 66 + 64] - m);
    stot += pp[c * 66 + 65] * w;
    acc += pp[c * 66 + d] * w;
  }
  ctxb[(size_t)b * L_TOT * E_DIM + h * 64 + d] = f2b(acc / stot);
}

// ---------------- windowed attention: one block per (w, h, b) ----------------
__global__ __launch_bounds__(256) void wattn_kernel(const u16* __restrict__ Qb,
                                                    const u16* __restrict__ Kb,
                                                    const u16* __restrict__ Vb,
                                                    u16* __restrict__ winctx) {
  int wdw = blockIdx.x;
  int h = blockIdx.y;
  int b = blockIdx.z;

  __shared__ u16 Ks[256][72];
  __shared__ u16 Vt[64][264];
  __shared__ u16 Ps[64][264];
  __shared__ u16 Qs[64][72];
  __shared__ float lsum[64];

  int t = threadIdx.x, lane = t & 63, wv = t >> 6;
  int g = lane >> 4, lr = lane & 15;
  size_t rowbase = (size_t)b * L_TOT + 1 + (size_t)wdw * 128;
  int hoff = h * 64;

#pragma unroll
  for (int pass = 0; pass < 4; pass++) {
    int i = pass * 64 + (t >> 2);
    int c = (t & 3) * 16;
    const uint4* p = (const uint4*)(Kb + (rowbase + i) * E_DIM + hoff + c);
    *(uint4*)&Ks[i][c] = p[0];
    *(uint4*)&Ks[i][c + 8] = p[1];
  }
#pragma unroll
  for (int rep = 0; rep < 8; rep++) {
    int u = rep * 256 + t;
    int i = u >> 3;
    int d0 = (u & 7) * 8;
    uint4 v = *(const uint4*)(Vb + (rowbase + i) * E_DIM + hoff + d0);
    const u16* pv = (const u16*)&v;
#pragma unroll
    for (int j = 0; j < 8; j++) Vt[d0 + j][i] = pv[j];
  }
  __syncthreads();

  for (int grp = 0; grp < 4; grp++) {
    {
      int i = t >> 2, c = (t & 3) * 16;
      const uint4* p = (const uint4*)(Qb + (rowbase + grp * 64 + i) * E_DIM + hoff + c);
      *(uint4*)&Qs[i][c] = p[0];
      *(uint4*)&Qs[i][c + 8] = p[1];
    }
    __syncthreads();

    bf16x8 qa0 = *(const bf16x8*)&Qs[wv * 16 + lr][g * 8];
    bf16x8 qa1 = *(const bf16x8*)&Qs[wv * 16 + lr][32 + g * 8];
    f4_t s[16];
#pragma unroll
    for (int ki = 0; ki < 16; ki++) {
      bf16x8 kb0 = *(const bf16x8*)&Ks[ki * 16 + lr][g * 8];
      bf16x8 kb1 = *(const bf16x8*)&Ks[ki * 16 + lr][32 + g * 8];
      f4_t z = {};
      z = mfma16(qa0, kb0, z);
      z = mfma16(qa1, kb1, z);
      s[ki] = z * 0.125f;
    }
    float m[4], sum[4];
#pragma unroll
    for (int r = 0; r < 4; r++) {
      float mx = -1e30f;
#pragma unroll
      for (int ki = 0; ki < 16; ki++) mx = fmaxf(mx, s[ki][r]);
      m[r] = mx;
    }
#pragma unroll
    for (int r = 0; r < 4; r++)
      for (int mask = 1; mask < 16; mask <<= 1) m[r] = fmaxf(m[r], __shfl_xor(m[r], mask));
#pragma unroll
    for (int r = 0; r < 4; r++) sum[r] = 0.f;
#pragma unroll
    for (int ki = 0; ki < 16; ki++) {
#pragma unroll
      for (int r = 0; r < 4; r++) {
        float p = __expf(s[ki][r] - m[r]);
        sum[r] += p;
        Ps[wv * 16 + g * 4 + r][ki * 16 + lr] = f2b(p);
      }
    }
#pragma unroll
    for (int r = 0; r < 4; r++)
      for (int mask = 1; mask < 16; mask <<= 1) sum[r] += __shfl_xor(sum[r], mask);
    if (lr == 0) {
#pragma unroll
      for (int r = 0; r < 4; r++) lsum[wv * 16 + g * 4 + r] = sum[r];
    }
    __syncthreads();

    f4_t o[4] = {};
#pragma unroll
    for (int kk = 0; kk < 8; kk++) {
      bf16x8 vb = *(const bf16x8*)&Vt[wv * 16 + lr][kk * 32 + g * 8];
#pragma unroll
      for (int mi = 0; mi < 4; mi++) {
        bf16x8 pa = *(const bf16x8*)&Ps[mi * 16 + lr][kk * 32 + g * 8];
        o[mi] = mfma16(pa, vb, o[mi]);
      }
    }
#pragma unroll
    for (int mi = 0; mi < 4; mi++) {
#pragma unroll
      for (int r = 0; r < 4; r++) {
        int qrow = mi * 16 + g * 4 + r;
        float val = o[mi][r] / lsum[qrow];
        size_t off = (((size_t)(b * NWIN + wdw) * 256 + grp * 64 + qrow) * E_DIM) + hoff + wv * 16 + lr;
        winctx[off] = f2b(val);
      }
    }
    __syncthreads();
  }
}

// ---------------- overlap-average combine: winctx -> ctxb rows 1..4096 ----------------
__global__ __launch_bounds__(256) void combine_kernel(const u16* __restrict__ winctx,
                                                      u16* __restrict__ ctxb) {
  int idx = blockIdx.x * 256 + threadIdx.x;
  int e0 = (idx & 127) * 8;
  int p = (idx >> 7) & 4095;
  int b = idx >> 19;
  int whi = p >> 7;
  if (whi > 30) whi = 30;
  int off_hi = p - whi * 128;
  int wlo = whi - 1;
  bool has_lo = (wlo >= 0) && (off_hi < 128);

  uint4 vhi = *(const uint4*)(winctx + (((size_t)(b * NWIN + whi) * 256 + off_hi) * E_DIM) + e0);
  const u16* ph = (const u16*)&vhi;
  float vals[8];
#pragma unroll
  for (int j = 0; j < 8; j++) vals[j] = b2f(ph[j]);
  if (has_lo) {
    uint4 vlo = *(const uint4*)(winctx + (((size_t)(b * NWIN + wlo) * 256 + off_hi + 128) * E_DIM) + e0);
    const u16* pl = (const u16*)&vlo;
#pragma unroll
    for (int j = 0; j < 8; j++) vals[j] = (vals[j] + b2f(pl[j])) * 0.5f;
  }
  u16 out[8];
#pragma unroll
  for (int j = 0; j < 8; j++) out[j] = f2b(vals[j]);
  *(uint4*)(ctxb + ((size_t)b * L_TOT + 1 + p) * E_DIM + e0) = *(uint4*)out;
}

// ---------------- launch ----------------
extern "C" void kernel_launch(void* const* d_in, const int* in_sizes, int n_in,
                              void* d_out, int out_size, void* d_ws, size_t ws_size,
                              hipStream_t stream) {
  const float* hs = (const float*)d_in[0];
  const float* Wq = (const float*)d_in[1];
  const float* bq = (const float*)d_in[2];
  const float* Wk = (const float*)d_in[3];
  const float* bk = (const float*)d_in[4];
  const float* Wv = (const float*)d_in[5];
  const float* bv = (const float*)d_in[6];
  const float* Wo = (const float*)d_in[7];
  const float* bo = (const float*)d_in[8];

  const size_t BLE = (size_t)M_ROWS * E_DIM;
  const size_t BLE_B = BLE * 2;
  const size_t EE = (size_t)E_DIM * E_DIM;

  char* ws = (char*)d_ws;
  u16* hsb = (u16*)(ws);
  u16* wtb = (u16*)(ws + BLE_B);                       // [4][1024][1024] = QKV concat + Wo
  u16* qkv = (u16*)(ws + BLE_B + 4 * EE * 2);
  u16* Qb = qkv;
  u16* Kb = qkv + BLE;
  u16* Vb = qkv + 2 * BLE;
  u16* ctxb = (u16*)(ws + BLE_B + 4 * EE * 2 + 3 * BLE_B);
  u16* winctx = (u16*)(ws + BLE_B + 4 * EE * 2 + 4 * BLE_B);
  float* gpart = (float*)(ws + BLE_B + 4 * EE * 2 + 4 * BLE_B +
                          (size_t)B_SZ * NWIN * 256 * E_DIM * 2);

  cvt_kernel<<<8194, 256, 0, stream>>>(hs, hsb, (int)(BLE / 4));
  wtrans_kernel<<<dim3(32, 32, 4), dim3(32, 8), 0, stream>>>(Wq, Wk, Wv, Wo, wtb);
  // QKV fused: N = 3072 -> 65 m-tiles x 24 n-tiles (BN=128) = 1560 blocks
  gemmB_kernel<0, 128><<<65 * 24, 256, 0, stream>>>(hsb, wtb, bq, bk, bv, qkv, M_ROWS, 24);
  gattn1_kernel<<<dim3(GCHUNKS, HHEADS, B_SZ), 256, 0, stream>>>(Qb, Kb, Vb, gpart);
  gattn2_kernel<<<32, 64, 0, stream>>>(gpart, ctxb);
  wattn_kernel<<<dim3(NWIN, HHEADS, B_SZ), 256, 0, stream>>>(Qb, Kb, Vb, winctx);
  combine_kernel<<<4096, 256, 0, stream>>>(winctx, ctxb);
  // output projection: N = 1024 -> 65 m-tiles x 16 n-tiles (BN=64) = 1040 blocks
  gemmB_kernel<1, 64><<<65 * 16, 256, 0, stream>>>(ctxb, wtb + 3 * EE, bo, bo, bo, d_out, M_ROWS, 16);
}

// Round 7
// 226.027 us; speedup vs baseline: 1.2550x; 1.1530x over previous
//
#include <hip/hip_runtime.h>

typedef unsigned short u16;
typedef unsigned int u32;
typedef __bf16 bf16x8 __attribute__((ext_vector_type(8)));
typedef float f4_t __attribute__((ext_vector_type(4)));

#define E_DIM 1024
#define L_TOT 4097
#define B_SZ 2
#define M_ROWS 8194   // B*L
#define NWIN 31
#define HHEADS 16
#define GCHUNKS 17    // ceil(4097/256)

__device__ __forceinline__ float b2f(u16 v) {
  union { u32 u; float f; } x; x.u = ((u32)v) << 16; return x.f;
}
__device__ __forceinline__ u16 f2b(float f) {
  union { float f; u32 u; } x; x.f = f;
  u32 r = (x.u + 0x7FFFu + ((x.u >> 16) & 1u)) >> 16;
  return (u16)r;
}
__device__ __forceinline__ f4_t mfma16(bf16x8 a, bf16x8 b, f4_t c) {
  return __builtin_amdgcn_mfma_f32_16x16x32_bf16(a, b, c, 0, 0, 0);
}
__device__ __forceinline__ u32 cvtpk(float lo, float hi) {
  u32 r;
  asm volatile("v_cvt_pk_bf16_f32 %0, %1, %2" : "=v"(r) : "v"(lo), "v"(hi));
  return r;
}

// async global->LDS, 16B per lane; LDS dest = wave-uniform base + lane*16
#define GLOAD16(gp, lp)                                                              \
  __builtin_amdgcn_global_load_lds(                                                  \
      (const __attribute__((address_space(1))) u32*)(gp),                            \
      (__attribute__((address_space(3))) u32*)(lp), 16, 0, 0)

// ---------------- fp32 -> bf16 convert (hidden states) ----------------
__global__ __launch_bounds__(256) void cvt_kernel(const float* __restrict__ src,
                                                  u16* __restrict__ dst, int n4) {
  int i = blockIdx.x * 256 + threadIdx.x;
  if (i >= n4) return;
  float4 v = ((const float4*)src)[i];
  u16 o[4] = {f2b(v.x), f2b(v.y), f2b(v.z), f2b(v.w)};
  *(uint2*)(dst + (size_t)i * 4) = *(uint2*)o;
}

// ---------------- weight transpose + convert: W (K x N) -> Wt (N x K) bf16 ----------------
__global__ __launch_bounds__(256) void wtrans_kernel(const float* __restrict__ w0,
                                                     const float* __restrict__ w1,
                                                     const float* __restrict__ w2,
                                                     const float* __restrict__ w3,
                                                     u16* __restrict__ wtb) {
  const float* src = blockIdx.z == 0 ? w0 : blockIdx.z == 1 ? w1 : blockIdx.z == 2 ? w2 : w3;
  u16* dst = wtb + (size_t)blockIdx.z * E_DIM * E_DIM;
  __shared__ float tile[32][33];
  int tx = threadIdx.x, ty = threadIdx.y;
  int x = blockIdx.x * 32 + tx;
  int y0 = blockIdx.y * 32;
  for (int j = ty; j < 32; j += 8) tile[j][tx] = src[(size_t)(y0 + j) * E_DIM + x];
  __syncthreads();
  for (int j = ty; j < 32; j += 8)
    dst[(size_t)(blockIdx.x * 32 + j) * E_DIM + blockIdx.y * 32 + tx] = f2b(tile[tx][j]);
}

// ================= GEMM: 128 x BN tile, BK=64, DOUBLE-BUFFERED, 256 thr ==========
template <int MODE, int BN>
__global__ __launch_bounds__(256) void gemmB_kernel(const u16* __restrict__ A,
                                                    const u16* __restrict__ Wt,
                                                    const float* __restrict__ b0,
                                                    const float* __restrict__ b1,
                                                    const float* __restrict__ b2,
                                                    void* __restrict__ outBase,
                                                    int M, int NTIL) {
  constexpr int NB = BN / 32;
  constexpr int ABUF = 128 * 64;
  constexpr int BBUF = BN * 64;
  __shared__ __align__(16) u16 sm[2 * ABUF + 2 * BBUF];
  u16* sA = sm;
  u16* sB = sm + 2 * ABUF;
  u16* epi16 = sm;
  float* epi32 = (float*)sm;

  int nwg = gridDim.x;
  int q8 = nwg >> 3, r8 = nwg & 7;
  int orig = blockIdx.x;
  int xcd = orig & 7, loc = orig >> 3;
  int wg = (xcd < r8 ? xcd * (q8 + 1) : r8 * (q8 + 1) + (xcd - r8) * q8) + loc;
  int mt = wg / NTIL, nt = wg - mt * NTIL;
  int m0 = mt * 128, n0 = nt * BN;

  int t = threadIdx.x, lane = t & 63, w = t >> 6;
  int wr = w >> 1, wc = w & 1;
  int lr = lane & 15, g = lane >> 4;

  int rsub = t >> 3;
  int ssrc = ((t & 7) ^ (rsub & 7)) * 8;
  int wbase = w * 512;
  const u16* pa[4];
  const u16* pb[NB];
#pragma unroll
  for (int c = 0; c < 4; c++) {
    int ra = m0 + c * 32 + rsub;
    if (ra >= M) ra = M - 1;
    pa[c] = A + (size_t)ra * 1024 + ssrc;
  }
#pragma unroll
  for (int c = 0; c < NB; c++) pb[c] = Wt + (size_t)(n0 + c * 32 + rsub) * 1024 + ssrc;

#define STAGE(bf, kt)                                                      \
  {                                                                        \
    int ko_ = (kt) * 64;                                                   \
    _Pragma("unroll") for (int c_ = 0; c_ < 4; c_++)                       \
        GLOAD16(pa[c_] + ko_, sA + (bf) * ABUF + c_ * 2048 + wbase);       \
    _Pragma("unroll") for (int c_ = 0; c_ < NB; c_++)                      \
        GLOAD16(pb[c_] + ko_, sB + (bf) * BBUF + c_ * 2048 + wbase);       \
  }

#define COMPUTE(bf)                                                            \
  {                                                                            \
    _Pragma("unroll") for (int kk_ = 0; kk_ < 2; kk_++) {                      \
      int sl_ = ((kk_ * 4 + g) ^ (lr & 7)) * 8;                                \
      bf16x8 av_[4], bv_[NB];                                                  \
      _Pragma("unroll") for (int i_ = 0; i_ < 4; i_++)                         \
          av_[i_] = *(const bf16x8*)&sA[(bf) * ABUF + (wr * 64 + i_ * 16 + lr) * 64 + sl_]; \
      _Pragma("unroll") for (int j_ = 0; j_ < NB; j_++)                        \
          bv_[j_] = *(const bf16x8*)&sB[(bf) * BBUF + (wc * (BN / 2) + j_ * 16 + lr) * 64 + sl_]; \
      _Pragma("unroll") for (int i_ = 0; i_ < 4; i_++)                         \
        _Pragma("unroll") for (int j_ = 0; j_ < NB; j_++)                      \
            acc[i_][j_] = mfma16(av_[i_], bv_[j_], acc[i_][j_]);               \
    }                                                                          \
  }

  f4_t acc[4][NB] = {};

  STAGE(0, 0);
  __syncthreads();

  int buf = 0;
  for (int kt = 0; kt < 15; ++kt) {
    STAGE(buf ^ 1, kt + 1);
    __builtin_amdgcn_sched_barrier(0);
    COMPUTE(buf);
    __syncthreads();
    buf ^= 1;
  }
  COMPUTE(buf);
  __syncthreads();

  if (MODE == 0) {
    int tsel = n0 >> 10, ncb = n0 & 1023;
    const float* bp = tsel == 0 ? b0 : (tsel == 1 ? b1 : b2);
#pragma unroll
    for (int j = 0; j < NB; j++) {
      int ncl = wc * (BN / 2) + j * 16 + lr;
      float bb = bp[ncb + ncl];
#pragma unroll
      for (int i = 0; i < 4; i++) {
        int mlb = wr * 64 + i * 16 + g * 4;
#pragma unroll
        for (int r = 0; r < 4; r++) epi16[(mlb + r) * 136 + ncl] = f2b(acc[i][j][r] + bb);
      }
    }
    __syncthreads();
    int row = t >> 1, half = t & 1;
    int m = m0 + row;
    if (m < M) {
      u16* op = (u16*)outBase + (size_t)tsel * ((size_t)M_ROWS * E_DIM) + (size_t)m * E_DIM + ncb + half * 64;
      const u16* lp = epi16 + row * 136 + half * 64;
#pragma unroll
      for (int qd = 0; qd < 8; qd++) ((uint4*)op)[qd] = ((const uint4*)lp)[qd];
    }
  } else {
#pragma unroll
    for (int j = 0; j < NB; j++) {
      int ncl = wc * (BN / 2) + j * 16 + lr;
      float bb = b0[n0 + ncl];
#pragma unroll
      for (int i = 0; i < 4; i++) {
        int mlb = wr * 64 + i * 16 + g * 4;
#pragma unroll
        for (int r = 0; r < 4; r++) epi32[(mlb + r) * 68 + ncl] = acc[i][j][r] + bb;
      }
    }
    __syncthreads();
    int row = t >> 1, half = t & 1;
    int m = m0 + row;
    if (m < M) {
      float* op = (float*)outBase + (size_t)m * E_DIM + n0 + half * 32;
      const float* lp = epi32 + row * 68 + half * 32;
#pragma unroll
      for (int qd = 0; qd < 8; qd++) ((float4*)op)[qd] = ((const float4*)lp)[qd];
    }
  }
#undef STAGE
#undef COMPUTE
}

// ---------------- global attention, phase 1: per-chunk partials ----------------
__global__ __launch_bounds__(256) void gattn1_kernel(const u16* __restrict__ Qb,
                                                     const u16* __restrict__ Kb,
                                                     const u16* __restrict__ Vb,
                                                     float* __restrict__ part) {
  int c = blockIdx.x;
  int h = blockIdx.y;
  int b = blockIdx.z;
  int t = threadIdx.x;
  __shared__ float qsh[64];
  __shared__ float red[4];
  __shared__ float psh[256];
  __shared__ float cred[4][64];

  size_t base = (size_t)b * L_TOT * E_DIM + h * 64;
  if (t < 64) qsh[t] = b2f(Qb[base + t]);
  __syncthreads();

  int row = c * 256 + t;
  bool valid = row < L_TOT;
  float dot = -1e30f;
  if (valid) {
    const u16* kp = Kb + base + (size_t)row * E_DIM;
    float acc = 0.f;
#pragma unroll
    for (int j = 0; j < 64; j += 8) {
      uint4 kv = *(const uint4*)(kp + j);
      const u16* kk = (const u16*)&kv;
#pragma unroll
      for (int q = 0; q < 8; q++) acc += qsh[j + q] * b2f(kk[q]);
    }
    dot = acc * 0.125f;
  }
  float m = dot;
  for (int mask = 1; mask < 64; mask <<= 1) m = fmaxf(m, __shfl_xor(m, mask));
  if ((t & 63) == 0) red[t >> 6] = m;
  __syncthreads();
  m = fmaxf(fmaxf(red[0], red[1]), fmaxf(red[2], red[3]));
  float p = valid ? __expf(dot - m) : 0.f;
  psh[t] = p;
  float s = p;
  for (int mask = 1; mask < 64; mask <<= 1) s += __shfl_xor(s, mask);
  __syncthreads();
  if ((t & 63) == 0) red[t >> 6] = s;
  __syncthreads();
  s = red[0] + red[1] + red[2] + red[3];

  int d = t & 63, gq = t >> 6;
  float acc = 0.f;
#pragma unroll 4
  for (int i = 0; i < 64; i++) {
    int sl = gq * 64 + i;
    int r2 = c * 256 + sl;
    if (r2 < L_TOT) acc += psh[sl] * b2f(Vb[base + (size_t)r2 * E_DIM + d]);
  }
  cred[gq][d] = acc;
  __syncthreads();
  if (t < 64) {
    float v = cred[0][t] + cred[1][t] + cred[2][t] + cred[3][t];
    float* pp = part + (((size_t)(b * HHEADS + h) * GCHUNKS + c) * 66);
    pp[t] = v;
    if (t == 0) { pp[64] = m; pp[65] = s; }
  }
}

// ---------------- global attention, phase 2: combine chunks ----------------
__global__ __launch_bounds__(64) void gattn2_kernel(const float* __restrict__ part,
                                                    u16* __restrict__ ctxb) {
  int bh = blockIdx.x;
  int b = bh >> 4, h = bh & 15;
  int d = threadIdx.x;
  const float* pp = part + ((size_t)(b * HHEADS + h) * GCHUNKS) * 66;
  float m = -1e30f;
#pragma unroll
  for (int c = 0; c < GCHUNKS; c++) m = fmaxf(m, pp[c * 66 + 64]);
  float stot = 0.f, acc = 0.f;
#pragma unroll
  for (int c = 0; c < GCHUNKS; c++) {
    float w = __expf(pp[c * 66 + 64] - m);
    stot += pp[c * 66 + 65] * w;
    acc += pp[c * 66 + d] * w;
  }
  ctxb[(size_t)b * L_TOT * E_DIM + h * 64 + d] = f2b(acc / stot);
}

// ========== windowed attention v2: swapped-QK^T, in-register softmax ==========
// One block per (w,h,b), 4 waves. S^T = mfma(K,Q): lane (g,lr) holds
// S[k=ki*16+g*4+r][q=lr] -> softmax lane-local + 2 shfl_xor. P repacked to bf16
// (cvt_pk) and redistributed in-register (8 shfl per k-tile) into PV A-frags.
// Q direct from global; K staged via global_load_lds + XOR swizzle; V staged
// transposed [d][k] with k-XOR swizzle (breaks the 8-row-stride bank collision).
// LDS 65 KB -> 2 blocks/CU. Zero barriers in the grp loop.
#define VT_IDX(d, k) ((d) * 264 + ((k) ^ ((((d) >> 3) & 7) << 3)))
__global__ __launch_bounds__(256) void wattn_kernel(const u16* __restrict__ Qb,
                                                    const u16* __restrict__ Kb,
                                                    const u16* __restrict__ Vb,
                                                    u16* __restrict__ winctx) {
  int wdw = blockIdx.x;
  int h = blockIdx.y;
  int b = blockIdx.z;

  __shared__ __align__(16) u16 Ks[256 * 64];   // 32 KB, GEMM-style swizzle
  __shared__ __align__(16) u16 Vt[64 * 264];   // 33 KB, [d][k] k-swizzled

  int t = threadIdx.x, lane = t & 63, wv = t >> 6;
  int g = lane >> 4, lr = lane & 15;
  size_t rowbase = (size_t)b * L_TOT + 1 + (size_t)wdw * 128;
  int hoff = h * 64;

  // ---- stage K: global_load_lds, linear dest, inverse-swizzled source ----
  {
    int rsub = t >> 3;                              // 0..31
    int ssrc = ((t & 7) ^ (rsub & 7)) * 8;
    const u16* kp = Kb + (rowbase + rsub) * E_DIM + hoff + ssrc;
#pragma unroll
    for (int c = 0; c < 8; c++)
      GLOAD16(kp + (size_t)c * 32 * E_DIM, Ks + c * 2048 + wv * 512);
  }
  // ---- stage V transposed with k-XOR swizzle ----
#pragma unroll
  for (int rep = 0; rep < 8; rep++) {
    int u = rep * 256 + t;
    int i = u >> 3;              // k position 0..255
    int d0 = (u & 7) * 8;
    uint4 v = *(const uint4*)(Vb + (rowbase + i) * E_DIM + hoff + d0);
    const u16* pv = (const u16*)&v;
#pragma unroll
    for (int j = 0; j < 8; j++) Vt[VT_IDX(d0 + j, i)] = pv[j];
  }
  __syncthreads();  // drains global_load_lds + ds_writes

  int slo = (2 * (g & 1)) * 16 + lr;
  int shi = slo + 16;

  for (int grp = 0; grp < 4; grp++) {
    int q0 = grp * 64 + wv * 16;
    // Q frags direct from global: lane (g,lr) -> Q[q0+lr][g*8.. / 32+g*8..]
    const u16* qp = Qb + (rowbase + q0 + lr) * E_DIM + hoff;
    bf16x8 qa0 = *(const bf16x8*)(qp + g * 8);
    bf16x8 qa1 = *(const bf16x8*)(qp + 32 + g * 8);

    // S^T phase: s[ki] holds S[k=ki*16+g*4+r][q=lr] (unscaled)
    f4_t s[16];
    __builtin_amdgcn_s_setprio(1);
#pragma unroll
    for (int ki = 0; ki < 16; ki++) {
      int row = ki * 16 + lr;
      bf16x8 ka0 = *(const bf16x8*)&Ks[row * 64 + ((g ^ (lr & 7)) << 3)];
      bf16x8 ka1 = *(const bf16x8*)&Ks[row * 64 + (((4 + g) ^ (lr & 7)) << 3)];
      f4_t z = {};
      z = mfma16(ka0, qa0, z);
      z = mfma16(ka1, qa1, z);
      s[ki] = z;
    }
    __builtin_amdgcn_s_setprio(0);

    // softmax over k for column q=lr (scale 1/8 folded into exp arg)
    float mx = -1e30f;
#pragma unroll
    for (int ki = 0; ki < 16; ki++) {
      mx = fmaxf(mx, fmaxf(fmaxf(s[ki][0], s[ki][1]), fmaxf(s[ki][2], s[ki][3])));
    }
    mx = fmaxf(mx, __shfl_xor(mx, 16));
    mx = fmaxf(mx, __shfl_xor(mx, 32));
    float mx8 = mx * 0.125f;
    float sum = 0.f;
    u32 pk[16][2];
#pragma unroll
    for (int ki = 0; ki < 16; ki++) {
      float p0 = __expf(fmaf(s[ki][0], 0.125f, -mx8));
      float p1 = __expf(fmaf(s[ki][1], 0.125f, -mx8));
      float p2 = __expf(fmaf(s[ki][2], 0.125f, -mx8));
      float p3 = __expf(fmaf(s[ki][3], 0.125f, -mx8));
      sum += (p0 + p1) + (p2 + p3);
      pk[ki][0] = cvtpk(p0, p1);
      pk[ki][1] = cvtpk(p2, p3);
    }
    sum += __shfl_xor(sum, 16);
    sum += __shfl_xor(sum, 32);
    float inv = 1.0f / sum;  // for q = lr (replicated over g)

    // redistribute P into PV A-frags: paw[kt] = P[q=lr][k=kt*32+g*8+j]
    u32 paw[8][4];
    bool hi = g >= 2;
#pragma unroll
    for (int kt = 0; kt < 8; kt++) {
      u32 v00 = __shfl((int)pk[kt * 2][0], slo);
      u32 v01 = __shfl((int)pk[kt * 2][1], slo);
      u32 v10 = __shfl((int)pk[kt * 2 + 1][0], slo);
      u32 v11 = __shfl((int)pk[kt * 2 + 1][1], slo);
      u32 w00 = __shfl((int)pk[kt * 2][0], shi);
      u32 w01 = __shfl((int)pk[kt * 2][1], shi);
      u32 w10 = __shfl((int)pk[kt * 2 + 1][0], shi);
      u32 w11 = __shfl((int)pk[kt * 2 + 1][1], shi);
      paw[kt][0] = hi ? v10 : v00;
      paw[kt][1] = hi ? v11 : v01;
      paw[kt][2] = hi ? w10 : w00;
      paw[kt][3] = hi ? w11 : w01;
    }

    // PV: O[q=g*4+r (16)][d=dtile*16+lr]
    f4_t o[4] = {};
    __builtin_amdgcn_s_setprio(1);
#pragma unroll
    for (int dtile = 0; dtile < 4; dtile++) {
      int d = dtile * 16 + lr;
      int dswz = (((d >> 3) & 7) << 3);
#pragma unroll
      for (int kt = 0; kt < 8; kt++) {
        int kphys = (kt * 32 + g * 8) ^ dswz;
        bf16x8 vb = *(const bf16x8*)&Vt[d * 264 + kphys];
        o[dtile] = mfma16(*(const bf16x8*)&paw[kt][0], vb, o[dtile]);
      }
    }
    __builtin_amdgcn_s_setprio(0);

    float invr[4];
#pragma unroll
    for (int r = 0; r < 4; r++) invr[r] = __shfl(inv, g * 4 + r);
    size_t orow = (size_t)(b * NWIN + wdw) * 256 + q0;
#pragma unroll
    for (int dtile = 0; dtile < 4; dtile++) {
#pragma unroll
      for (int r = 0; r < 4; r++) {
        winctx[(orow + g * 4 + r) * E_DIM + hoff + dtile * 16 + lr] =
            f2b(o[dtile][r] * invr[r]);
      }
    }
  }
}

// ---------------- overlap-average combine: winctx -> ctxb rows 1..4096 ----------------
__global__ __launch_bounds__(256) void combine_kernel(const u16* __restrict__ winctx,
                                                      u16* __restrict__ ctxb) {
  int idx = blockIdx.x * 256 + threadIdx.x;
  int e0 = (idx & 127) * 8;
  int p = (idx >> 7) & 4095;
  int b = idx >> 19;
  int whi = p >> 7;
  if (whi > 30) whi = 30;
  int off_hi = p - whi * 128;
  int wlo = whi - 1;
  bool has_lo = (wlo >= 0) && (off_hi < 128);

  uint4 vhi = *(const uint4*)(winctx + (((size_t)(b * NWIN + whi) * 256 + off_hi) * E_DIM) + e0);
  const u16* ph = (const u16*)&vhi;
  float vals[8];
#pragma unroll
  for (int j = 0; j < 8; j++) vals[j] = b2f(ph[j]);
  if (has_lo) {
    uint4 vlo = *(const uint4*)(winctx + (((size_t)(b * NWIN + wlo) * 256 + off_hi + 128) * E_DIM) + e0);
    const u16* pl = (const u16*)&vlo;
#pragma unroll
    for (int j = 0; j < 8; j++) vals[j] = (vals[j] + b2f(pl[j])) * 0.5f;
  }
  u16 out[8];
#pragma unroll
  for (int j = 0; j < 8; j++) out[j] = f2b(vals[j]);
  *(uint4*)(ctxb + ((size_t)b * L_TOT + 1 + p) * E_DIM + e0) = *(uint4*)out;
}

// ---------------- launch ----------------
extern "C" void kernel_launch(void* const* d_in, const int* in_sizes, int n_in,
                              void* d_out, int out_size, void* d_ws, size_t ws_size,
                              hipStream_t stream) {
  const float* hs = (const float*)d_in[0];
  const float* Wq = (const float*)d_in[1];
  const float* bq = (const float*)d_in[2];
  const float* Wk = (const float*)d_in[3];
  const float* bk = (const float*)d_in[4];
  const float* Wv = (const float*)d_in[5];
  const float* bv = (const float*)d_in[6];
  const float* Wo = (const float*)d_in[7];
  const float* bo = (const float*)d_in[8];

  const size_t BLE = (size_t)M_ROWS * E_DIM;
  const size_t BLE_B = BLE * 2;
  const size_t EE = (size_t)E_DIM * E_DIM;

  char* ws = (char*)d_ws;
  u16* hsb = (u16*)(ws);
  u16* wtb = (u16*)(ws + BLE_B);
  u16* qkv = (u16*)(ws + BLE_B + 4 * EE * 2);
  u16* Qb = qkv;
  u16* Kb = qkv + BLE;
  u16* Vb = qkv + 2 * BLE;
  u16* ctxb = (u16*)(ws + BLE_B + 4 * EE * 2 + 3 * BLE_B);
  u16* winctx = (u16*)(ws + BLE_B + 4 * EE * 2 + 4 * BLE_B);
  float* gpart = (float*)(ws + BLE_B + 4 * EE * 2 + 4 * BLE_B +
                          (size_t)B_SZ * NWIN * 256 * E_DIM * 2);

  cvt_kernel<<<8194, 256, 0, stream>>>(hs, hsb, (int)(BLE / 4));
  wtrans_kernel<<<dim3(32, 32, 4), dim3(32, 8), 0, stream>>>(Wq, Wk, Wv, Wo, wtb);
  gemmB_kernel<0, 128><<<65 * 24, 256, 0, stream>>>(hsb, wtb, bq, bk, bv, qkv, M_ROWS, 24);
  gattn1_kernel<<<dim3(GCHUNKS, HHEADS, B_SZ), 256, 0, stream>>>(Qb, Kb, Vb, gpart);
  gattn2_kernel<<<32, 64, 0, stream>>>(gpart, ctxb);
  wattn_kernel<<<dim3(NWIN, HHEADS, B_SZ), 256, 0, stream>>>(Qb, Kb, Vb, winctx);
  combine_kernel<<<4096, 256, 0, stream>>>(winctx, ctxb);
  gemmB_kernel<1, 64><<<65 * 16, 256, 0, stream>>>(ctxb, wtb + 3 * EE, bo, bo, bo, d_out, M_ROWS, 16);
}

// Round 8
// 224.424 us; speedup vs baseline: 1.2640x; 1.0071x over previous
//
#include <hip/hip_runtime.h>

typedef unsigned short u16;
typedef unsigned int u32;
typedef __bf16 bf16x8 __attribute__((ext_vector_type(8)));
typedef float f4_t __attribute__((ext_vector_type(4)));

#define E_DIM 1024
#define L_TOT 4097
#define B_SZ 2
#define M_ROWS 8194   // B*L
#define NWIN 31
#define HHEADS 16
#define GCHUNKS 17    // ceil(4097/256)

__device__ __forceinline__ float b2f(u16 v) {
  union { u32 u; float f; } x; x.u = ((u32)v) << 16; return x.f;
}
__device__ __forceinline__ u16 f2b(float f) {
  union { float f; u32 u; } x; x.f = f;
  u32 r = (x.u + 0x7FFFu + ((x.u >> 16) & 1u)) >> 16;
  return (u16)r;
}
__device__ __forceinline__ f4_t mfma16(bf16x8 a, bf16x8 b, f4_t c) {
  return __builtin_amdgcn_mfma_f32_16x16x32_bf16(a, b, c, 0, 0, 0);
}
__device__ __forceinline__ u32 cvtpk(float lo, float hi) {
  u32 r;
  asm volatile("v_cvt_pk_bf16_f32 %0, %1, %2" : "=v"(r) : "v"(lo), "v"(hi));
  return r;
}

// async global->LDS, 16B per lane; LDS dest = wave-uniform base + lane*16
#define GLOAD16(gp, lp)                                                              \
  __builtin_amdgcn_global_load_lds(                                                  \
      (const __attribute__((address_space(1))) u32*)(gp),                            \
      (__attribute__((address_space(3))) u32*)(lp), 16, 0, 0)

#define WAITVM(N) asm volatile("s_waitcnt vmcnt(" #N ")" ::: "memory")

// ---------------- fp32 -> bf16 convert (hidden states) ----------------
__global__ __launch_bounds__(256) void cvt_kernel(const float* __restrict__ src,
                                                  u16* __restrict__ dst, int n4) {
  int i = blockIdx.x * 256 + threadIdx.x;
  if (i >= n4) return;
  float4 v = ((const float4*)src)[i];
  u16 o[4] = {f2b(v.x), f2b(v.y), f2b(v.z), f2b(v.w)};
  *(uint2*)(dst + (size_t)i * 4) = *(uint2*)o;
}

// ---------------- weight transpose + convert: W (K x N) -> Wt (N x K) bf16 ----------------
__global__ __launch_bounds__(256) void wtrans_kernel(const float* __restrict__ w0,
                                                     const float* __restrict__ w1,
                                                     const float* __restrict__ w2,
                                                     const float* __restrict__ w3,
                                                     u16* __restrict__ wtb) {
  const float* src = blockIdx.z == 0 ? w0 : blockIdx.z == 1 ? w1 : blockIdx.z == 2 ? w2 : w3;
  u16* dst = wtb + (size_t)blockIdx.z * E_DIM * E_DIM;
  __shared__ float tile[32][33];
  int tx = threadIdx.x, ty = threadIdx.y;
  int x = blockIdx.x * 32 + tx;
  int y0 = blockIdx.y * 32;
  for (int j = ty; j < 32; j += 8) tile[j][tx] = src[(size_t)(y0 + j) * E_DIM + x];
  __syncthreads();
  for (int j = ty; j < 32; j += 8)
    dst[(size_t)(blockIdx.x * 32 + j) * E_DIM + blockIdx.y * 32 + tx] = f2b(tile[tx][j]);
}

// ================= GEMM: 128 x BN tile, BK=64, depth-2 prefetch, counted vmcnt ====
// C(M x NTIL*BN) = A(M x 1024) * Wt^T + bias; Wt stored [N][1024].
// r7 change: counted vmcnt (never 0 mid-loop). Prologue stages tiles 0,1; per iter
// waits only the OLDEST stage (issued 2 iters earlier), computes, barriers, stages
// kt+2. Race-free: per-wave vmcnt + s_barrier => all waves' DMA for consumed buf
// landed; post-compute barrier separates reads from re-staging DMA.
// MODE 0 (BN=128): bf16 demux to 3 tensors [M_ROWS][1024]. MODE 1 (BN=64): fp32.
template <int MODE, int BN>
__global__ __launch_bounds__(256) void gemmB_kernel(const u16* __restrict__ A,
                                                    const u16* __restrict__ Wt,
                                                    const float* __restrict__ b0,
                                                    const float* __restrict__ b1,
                                                    const float* __restrict__ b2,
                                                    void* __restrict__ outBase,
                                                    int M, int NTIL) {
  constexpr int NB = BN / 32;       // loads per B-stage; acc cols per wave
  constexpr int ABUF = 128 * 64;
  constexpr int BBUF = BN * 64;
  __shared__ __align__(16) u16 sm[2 * ABUF + 2 * BBUF];
  u16* sA = sm;
  u16* sB = sm + 2 * ABUF;
  u16* epi16 = sm;
  float* epi32 = (float*)sm;

  int nwg = gridDim.x;
  int q8 = nwg >> 3, r8 = nwg & 7;
  int orig = blockIdx.x;
  int xcd = orig & 7, loc = orig >> 3;
  int wg = (xcd < r8 ? xcd * (q8 + 1) : r8 * (q8 + 1) + (xcd - r8) * q8) + loc;
  int mt = wg / NTIL, nt = wg - mt * NTIL;
  int m0 = mt * 128, n0 = nt * BN;

  int t = threadIdx.x, lane = t & 63, w = t >> 6;
  int wr = w >> 1, wc = w & 1;
  int lr = lane & 15, g = lane >> 4;

  int rsub = t >> 3;
  int ssrc = ((t & 7) ^ (rsub & 7)) * 8;
  int wbase = w * 512;
  const u16* pa[4];
  const u16* pb[NB];
#pragma unroll
  for (int c = 0; c < 4; c++) {
    int ra = m0 + c * 32 + rsub;
    if (ra >= M) ra = M - 1;
    pa[c] = A + (size_t)ra * 1024 + ssrc;
  }
#pragma unroll
  for (int c = 0; c < NB; c++) pb[c] = Wt + (size_t)(n0 + c * 32 + rsub) * 1024 + ssrc;

#define STAGE(bf, kt)                                                      \
  {                                                                        \
    int ko_ = (kt) * 64;                                                   \
    _Pragma("unroll") for (int c_ = 0; c_ < 4; c_++)                       \
        GLOAD16(pa[c_] + ko_, sA + (bf) * ABUF + c_ * 2048 + wbase);       \
    _Pragma("unroll") for (int c_ = 0; c_ < NB; c_++)                      \
        GLOAD16(pb[c_] + ko_, sB + (bf) * BBUF + c_ * 2048 + wbase);       \
  }

#define COMPUTE(bf)                                                            \
  {                                                                            \
    _Pragma("unroll") for (int kk_ = 0; kk_ < 2; kk_++) {                      \
      int sl_ = ((kk_ * 4 + g) ^ (lr & 7)) * 8;                                \
      bf16x8 av_[4], bv_[NB];                                                  \
      _Pragma("unroll") for (int i_ = 0; i_ < 4; i_++)                         \
          av_[i_] = *(const bf16x8*)&sA[(bf) * ABUF + (wr * 64 + i_ * 16 + lr) * 64 + sl_]; \
      _Pragma("unroll") for (int j_ = 0; j_ < NB; j_++)                        \
          bv_[j_] = *(const bf16x8*)&sB[(bf) * BBUF + (wc * (BN / 2) + j_ * 16 + lr) * 64 + sl_]; \
      _Pragma("unroll") for (int i_ = 0; i_ < 4; i_++)                         \
        _Pragma("unroll") for (int j_ = 0; j_ < NB; j_++)                      \
            acc[i_][j_] = mfma16(av_[i_], bv_[j_], acc[i_][j_]);               \
    }                                                                          \
  }

  f4_t acc[4][NB] = {};

  // prologue: 2 tiles in flight (depth-2 pipeline)
  STAGE(0, 0);
  STAGE(1, 1);

  int buf = 0;
  for (int kt = 0; kt < 16; ++kt) {
    if (kt < 15) {
      // wait only the oldest stage (issued 2 iterations ago); newer stays in flight
      if constexpr (NB == 4) { WAITVM(8); } else { WAITVM(6); }
    } else {
      WAITVM(0);
    }
    __builtin_amdgcn_sched_barrier(0);
    __builtin_amdgcn_s_barrier();            // all waves' DMA for buf landed
    __builtin_amdgcn_sched_barrier(0);
    COMPUTE(buf);
    __builtin_amdgcn_sched_barrier(0);
    __builtin_amdgcn_s_barrier();            // all reads of buf done
    __builtin_amdgcn_sched_barrier(0);
    if (kt < 14) STAGE(buf, kt + 2);         // refill this buffer
    buf ^= 1;
  }
  __syncthreads();  // protect LDS before epilogue aliasing

  if (MODE == 0) {
    int tsel = n0 >> 10, ncb = n0 & 1023;
    const float* bp = tsel == 0 ? b0 : (tsel == 1 ? b1 : b2);
#pragma unroll
    for (int j = 0; j < NB; j++) {
      int ncl = wc * (BN / 2) + j * 16 + lr;
      float bb = bp[ncb + ncl];
#pragma unroll
      for (int i = 0; i < 4; i++) {
        int mlb = wr * 64 + i * 16 + g * 4;
#pragma unroll
        for (int r = 0; r < 4; r++) epi16[(mlb + r) * 136 + ncl] = f2b(acc[i][j][r] + bb);
      }
    }
    __syncthreads();
    int row = t >> 1, half = t & 1;
    int m = m0 + row;
    if (m < M) {
      u16* op = (u16*)outBase + (size_t)tsel * ((size_t)M_ROWS * E_DIM) + (size_t)m * E_DIM + ncb + half * 64;
      const u16* lp = epi16 + row * 136 + half * 64;
#pragma unroll
      for (int qd = 0; qd < 8; qd++) ((uint4*)op)[qd] = ((const uint4*)lp)[qd];
    }
  } else {
#pragma unroll
    for (int j = 0; j < NB; j++) {
      int ncl = wc * (BN / 2) + j * 16 + lr;
      float bb = b0[n0 + ncl];
#pragma unroll
      for (int i = 0; i < 4; i++) {
        int mlb = wr * 64 + i * 16 + g * 4;
#pragma unroll
        for (int r = 0; r < 4; r++) epi32[(mlb + r) * 68 + ncl] = acc[i][j][r] + bb;
      }
    }
    __syncthreads();
    int row = t >> 1, half = t & 1;
    int m = m0 + row;
    if (m < M) {
      float* op = (float*)outBase + (size_t)m * E_DIM + n0 + half * 32;
      const float* lp = epi32 + row * 68 + half * 32;
#pragma unroll
      for (int qd = 0; qd < 8; qd++) ((float4*)op)[qd] = ((const float4*)lp)[qd];
    }
  }
#undef STAGE
#undef COMPUTE
}

// ---------------- global attention, phase 1: per-chunk partials ----------------
__global__ __launch_bounds__(256) void gattn1_kernel(const u16* __restrict__ Qb,
                                                     const u16* __restrict__ Kb,
                                                     const u16* __restrict__ Vb,
                                                     float* __restrict__ part) {
  int c = blockIdx.x;
  int h = blockIdx.y;
  int b = blockIdx.z;
  int t = threadIdx.x;
  __shared__ float qsh[64];
  __shared__ float red[4];
  __shared__ float psh[256];
  __shared__ float cred[4][64];

  size_t base = (size_t)b * L_TOT * E_DIM + h * 64;
  if (t < 64) qsh[t] = b2f(Qb[base + t]);
  __syncthreads();

  int row = c * 256 + t;
  bool valid = row < L_TOT;
  float dot = -1e30f;
  if (valid) {
    const u16* kp = Kb + base + (size_t)row * E_DIM;
    float acc = 0.f;
#pragma unroll
    for (int j = 0; j < 64; j += 8) {
      uint4 kv = *(const uint4*)(kp + j);
      const u16* kk = (const u16*)&kv;
#pragma unroll
      for (int q = 0; q < 8; q++) acc += qsh[j + q] * b2f(kk[q]);
    }
    dot = acc * 0.125f;
  }
  float m = dot;
  for (int mask = 1; mask < 64; mask <<= 1) m = fmaxf(m, __shfl_xor(m, mask));
  if ((t & 63) == 0) red[t >> 6] = m;
  __syncthreads();
  m = fmaxf(fmaxf(red[0], red[1]), fmaxf(red[2], red[3]));
  float p = valid ? __expf(dot - m) : 0.f;
  psh[t] = p;
  float s = p;
  for (int mask = 1; mask < 64; mask <<= 1) s += __shfl_xor(s, mask);
  __syncthreads();
  if ((t & 63) == 0) red[t >> 6] = s;
  __syncthreads();
  s = red[0] + red[1] + red[2] + red[3];

  int d = t & 63, gq = t >> 6;
  float acc = 0.f;
#pragma unroll 4
  for (int i = 0; i < 64; i++) {
    int sl = gq * 64 + i;
    int r2 = c * 256 + sl;
    if (r2 < L_TOT) acc += psh[sl] * b2f(Vb[base + (size_t)r2 * E_DIM + d]);
  }
  cred[gq][d] = acc;
  __syncthreads();
  if (t < 64) {
    float v = cred[0][t] + cred[1][t] + cred[2][t] + cred[3][t];
    float* pp = part + (((size_t)(b * HHEADS + h) * GCHUNKS + c) * 66);
    pp[t] = v;
    if (t == 0) { pp[64] = m; pp[65] = s; }
  }
}

// ---------------- global attention, phase 2: combine chunks ----------------
__global__ __launch_bounds__(64) void gattn2_kernel(const float* __restrict__ part,
                                                    u16* __restrict__ ctxb) {
  int bh = blockIdx.x;
  int b = bh >> 4, h = bh & 15;
  int d = threadIdx.x;
  const float* pp = part + ((size_t)(b * HHEADS + h) * GCHUNKS) * 66;
  float m = -1e30f;
#pragma unroll
  for (int c = 0; c < GCHUNKS; c++) m = fmaxf(m, pp[c * 66 + 64]);
  float stot = 0.f, acc = 0.f;
#pragma unroll
  for (int c = 0; c < GCHUNKS; c++) {
    float w = __expf(pp[c * 66 + 64] - m);
    stot += pp[c * 66 + 65] * w;
    acc += pp[c * 66 + d] * w;
  }
  ctxb[(size_t)b * L_TOT * E_DIM + h * 64 + d] = f2b(acc / stot);
}

// ========== windowed attention v2: swapped-QK^T, in-register softmax ==========
#define VT_IDX(d, k) ((d) * 264 + ((k) ^ ((((d) >> 3) & 7) << 3)))
__global__ __launch_bounds__(256) void wattn_kernel(const u16* __restrict__ Qb,
                                                    const u16* __restrict__ Kb,
                                                    const u16* __restrict__ Vb,
                                                    u16* __restrict__ winctx) {
  int wdw = blockIdx.x;
  int h = blockIdx.y;
  int b = blockIdx.z;

  __shared__ __align__(16) u16 Ks[256 * 64];   // 32 KB, GEMM-style swizzle
  __shared__ __align__(16) u16 Vt[64 * 264];   // 33 KB, [d][k] k-swizzled

  int t = threadIdx.x, lane = t & 63, wv = t >> 6;
  int g = lane >> 4, lr = lane & 15;
  size_t rowbase = (size_t)b * L_TOT + 1 + (size_t)wdw * 128;
  int hoff = h * 64;

  {
    int rsub = t >> 3;
    int ssrc = ((t & 7) ^ (rsub & 7)) * 8;
    const u16* kp = Kb + (rowbase + rsub) * E_DIM + hoff + ssrc;
#pragma unroll
    for (int c = 0; c < 8; c++)
      GLOAD16(kp + (size_t)c * 32 * E_DIM, Ks + c * 2048 + wv * 512);
  }
#pragma unroll
  for (int rep = 0; rep < 8; rep++) {
    int u = rep * 256 + t;
    int i = u >> 3;
    int d0 = (u & 7) * 8;
    uint4 v = *(const uint4*)(Vb + (rowbase + i) * E_DIM + hoff + d0);
    const u16* pv = (const u16*)&v;
#pragma unroll
    for (int j = 0; j < 8; j++) Vt[VT_IDX(d0 + j, i)] = pv[j];
  }
  __syncthreads();

  int slo = (2 * (g & 1)) * 16 + lr;
  int shi = slo + 16;

  for (int grp = 0; grp < 4; grp++) {
    int q0 = grp * 64 + wv * 16;
    const u16* qp = Qb + (rowbase + q0 + lr) * E_DIM + hoff;
    bf16x8 qa0 = *(const bf16x8*)(qp + g * 8);
    bf16x8 qa1 = *(const bf16x8*)(qp + 32 + g * 8);

    f4_t s[16];
    __builtin_amdgcn_s_setprio(1);
#pragma unroll
    for (int ki = 0; ki < 16; ki++) {
      int row = ki * 16 + lr;
      bf16x8 ka0 = *(const bf16x8*)&Ks[row * 64 + ((g ^ (lr & 7)) << 3)];
      bf16x8 ka1 = *(const bf16x8*)&Ks[row * 64 + (((4 + g) ^ (lr & 7)) << 3)];
      f4_t z = {};
      z = mfma16(ka0, qa0, z);
      z = mfma16(ka1, qa1, z);
      s[ki] = z;
    }
    __builtin_amdgcn_s_setprio(0);

    float mx = -1e30f;
#pragma unroll
    for (int ki = 0; ki < 16; ki++) {
      mx = fmaxf(mx, fmaxf(fmaxf(s[ki][0], s[ki][1]), fmaxf(s[ki][2], s[ki][3])));
    }
    mx = fmaxf(mx, __shfl_xor(mx, 16));
    mx = fmaxf(mx, __shfl_xor(mx, 32));
    float mx8 = mx * 0.125f;
    float sum = 0.f;
    u32 pk[16][2];
#pragma unroll
    for (int ki = 0; ki < 16; ki++) {
      float p0 = __expf(fmaf(s[ki][0], 0.125f, -mx8));
      float p1 = __expf(fmaf(s[ki][1], 0.125f, -mx8));
      float p2 = __expf(fmaf(s[ki][2], 0.125f, -mx8));
      float p3 = __expf(fmaf(s[ki][3], 0.125f, -mx8));
      sum += (p0 + p1) + (p2 + p3);
      pk[ki][0] = cvtpk(p0, p1);
      pk[ki][1] = cvtpk(p2, p3);
    }
    sum += __shfl_xor(sum, 16);
    sum += __shfl_xor(sum, 32);
    float inv = 1.0f / sum;

    u32 paw[8][4];
    bool hi = g >= 2;
#pragma unroll
    for (int kt = 0; kt < 8; kt++) {
      u32 v00 = __shfl((int)pk[kt * 2][0], slo);
      u32 v01 = __shfl((int)pk[kt * 2][1], slo);
      u32 v10 = __shfl((int)pk[kt * 2 + 1][0], slo);
      u32 v11 = __shfl((int)pk[kt * 2 + 1][1], slo);
      u32 w00 = __shfl((int)pk[kt * 2][0], shi);
      u32 w01 = __shfl((int)pk[kt * 2][1], shi);
      u32 w10 = __shfl((int)pk[kt * 2 + 1][0], shi);
      u32 w11 = __shfl((int)pk[kt * 2 + 1][1], shi);
      paw[kt][0] = hi ? v10 : v00;
      paw[kt][1] = hi ? v11 : v01;
      paw[kt][2] = hi ? w10 : w00;
      paw[kt][3] = hi ? w11 : w01;
    }

    f4_t o[4] = {};
    __builtin_amdgcn_s_setprio(1);
#pragma unroll
    for (int dtile = 0; dtile < 4; dtile++) {
      int d = dtile * 16 + lr;
      int dswz = (((d >> 3) & 7) << 3);
#pragma unroll
      for (int kt = 0; kt < 8; kt++) {
        int kphys = (kt * 32 + g * 8) ^ dswz;
        bf16x8 vb = *(const bf16x8*)&Vt[d * 264 + kphys];
        o[dtile] = mfma16(*(const bf16x8*)&paw[kt][0], vb, o[dtile]);
      }
    }
    __builtin_amdgcn_s_setprio(0);

    float invr[4];
#pragma unroll
    for (int r = 0; r < 4; r++) invr[r] = __shfl(inv, g * 4 + r);
    size_t orow = (size_t)(b * NWIN + wdw) * 256 + q0;
#pragma unroll
    for (int dtile = 0; dtile < 4; dtile++) {
#pragma unroll
      for (int r = 0; r < 4; r++) {
        winctx[(orow + g * 4 + r) * E_DIM + hoff + dtile * 16 + lr] =
            f2b(o[dtile][r] * invr[r]);
      }
    }
  }
}

// ---------------- overlap-average combine: winctx -> ctxb rows 1..4096 ----------------
__global__ __launch_bounds__(256) void combine_kernel(const u16* __restrict__ winctx,
                                                      u16* __restrict__ ctxb) {
  int idx = blockIdx.x * 256 + threadIdx.x;
  int e0 = (idx & 127) * 8;
  int p = (idx >> 7) & 4095;
  int b = idx >> 19;
  int whi = p >> 7;
  if (whi > 30) whi = 30;
  int off_hi = p - whi * 128;
  int wlo = whi - 1;
  bool has_lo = (wlo >= 0) && (off_hi < 128);

  uint4 vhi = *(const uint4*)(winctx + (((size_t)(b * NWIN + whi) * 256 + off_hi) * E_DIM) + e0);
  const u16* ph = (const u16*)&vhi;
  float vals[8];
#pragma unroll
  for (int j = 0; j < 8; j++) vals[j] = b2f(ph[j]);
  if (has_lo) {
    uint4 vlo = *(const uint4*)(winctx + (((size_t)(b * NWIN + wlo) * 256 + off_hi + 128) * E_DIM) + e0);
    const u16* pl = (const u16*)&vlo;
#pragma unroll
    for (int j = 0; j < 8; j++) vals[j] = (vals[j] + b2f(pl[j])) * 0.5f;
  }
  u16 out[8];
#pragma unroll
  for (int j = 0; j < 8; j++) out[j] = f2b(vals[j]);
  *(uint4*)(ctxb + ((size_t)b * L_TOT + 1 + p) * E_DIM + e0) = *(uint4*)out;
}

// ---------------- launch ----------------
extern "C" void kernel_launch(void* const* d_in, const int* in_sizes, int n_in,
                              void* d_out, int out_size, void* d_ws, size_t ws_size,
                              hipStream_t stream) {
  const float* hs = (const float*)d_in[0];
  const float* Wq = (const float*)d_in[1];
  const float* bq = (const float*)d_in[2];
  const float* Wk = (const float*)d_in[3];
  const float* bk = (const float*)d_in[4];
  const float* Wv = (const float*)d_in[5];
  const float* bv = (const float*)d_in[6];
  const float* Wo = (const float*)d_in[7];
  const float* bo = (const float*)d_in[8];

  const size_t BLE = (size_t)M_ROWS * E_DIM;
  const size_t BLE_B = BLE * 2;
  const size_t EE = (size_t)E_DIM * E_DIM;

  char* ws = (char*)d_ws;
  u16* hsb = (u16*)(ws);
  u16* wtb = (u16*)(ws + BLE_B);
  u16* qkv = (u16*)(ws + BLE_B + 4 * EE * 2);
  u16* Qb = qkv;
  u16* Kb = qkv + BLE;
  u16* Vb = qkv + 2 * BLE;
  u16* ctxb = (u16*)(ws + BLE_B + 4 * EE * 2 + 3 * BLE_B);
  u16* winctx = (u16*)(ws + BLE_B + 4 * EE * 2 + 4 * BLE_B);
  float* gpart = (float*)(ws + BLE_B + 4 * EE * 2 + 4 * BLE_B +
                          (size_t)B_SZ * NWIN * 256 * E_DIM * 2);

  cvt_kernel<<<8194, 256, 0, stream>>>(hs, hsb, (int)(BLE / 4));
  wtrans_kernel<<<dim3(32, 32, 4), dim3(32, 8), 0, stream>>>(Wq, Wk, Wv, Wo, wtb);
  gemmB_kernel<0, 128><<<65 * 24, 256, 0, stream>>>(hsb, wtb, bq, bk, bv, qkv, M_ROWS, 24);
  gattn1_kernel<<<dim3(GCHUNKS, HHEADS, B_SZ), 256, 0, stream>>>(Qb, Kb, Vb, gpart);
  gattn2_kernel<<<32, 64, 0, stream>>>(gpart, ctxb);
  wattn_kernel<<<dim3(NWIN, HHEADS, B_SZ), 256, 0, stream>>>(Qb, Kb, Vb, winctx);
  combine_kernel<<<4096, 256, 0, stream>>>(winctx, ctxb);
  gemmB_kernel<1, 64><<<65 * 16, 256, 0, stream>>>(ctxb, wtb + 3 * EE, bo, bo, bo, d_out, M_ROWS, 16);
}

// Round 9
// 218.839 us; speedup vs baseline: 1.2963x; 1.0255x over previous
//
#include <hip/hip_runtime.h>

typedef unsigned short u16;
typedef unsigned int u32;
typedef __bf16 bf16x8 __attribute__((ext_vector_type(8)));
typedef float f4_t __attribute__((ext_vector_type(4)));

#define E_DIM 1024
#define L_TOT 4097
#define B_SZ 2
#define M_ROWS 8194   // B*L
#define NWIN 31
#define HHEADS 16
#define GCHUNKS 17    // ceil(4097/256)

__device__ __forceinline__ float b2f(u16 v) {
  union { u32 u; float f; } x; x.u = ((u32)v) << 16; return x.f;
}
__device__ __forceinline__ u16 f2b(float f) {
  union { float f; u32 u; } x; x.f = f;
  u32 r = (x.u + 0x7FFFu + ((x.u >> 16) & 1u)) >> 16;
  return (u16)r;
}
__device__ __forceinline__ f4_t mfma16(bf16x8 a, bf16x8 b, f4_t c) {
  return __builtin_amdgcn_mfma_f32_16x16x32_bf16(a, b, c, 0, 0, 0);
}
__device__ __forceinline__ u32 cvtpk(float lo, float hi) {
  u32 r;
  asm volatile("v_cvt_pk_bf16_f32 %0, %1, %2" : "=v"(r) : "v"(lo), "v"(hi));
  return r;
}

// async global->LDS, 16B per lane; LDS dest = wave-uniform base + lane*16
#define GLOAD16(gp, lp)                                                              \
  __builtin_amdgcn_global_load_lds(                                                  \
      (const __attribute__((address_space(1))) u32*)(gp),                            \
      (__attribute__((address_space(3))) u32*)(lp), 16, 0, 0)

#define WAITVM(N) asm volatile("s_waitcnt vmcnt(" #N ")" ::: "memory")
#define SBAR                                  \
  {                                           \
    __builtin_amdgcn_sched_barrier(0);        \
    __builtin_amdgcn_s_barrier();             \
    __builtin_amdgcn_sched_barrier(0);        \
  }

// ---------------- fp32 -> bf16 convert (hidden states) ----------------
__global__ __launch_bounds__(256) void cvt_kernel(const float* __restrict__ src,
                                                  u16* __restrict__ dst, int n4) {
  int i = blockIdx.x * 256 + threadIdx.x;
  if (i >= n4) return;
  float4 v = ((const float4*)src)[i];
  u16 o[4] = {f2b(v.x), f2b(v.y), f2b(v.z), f2b(v.w)};
  *(uint2*)(dst + (size_t)i * 4) = *(uint2*)o;
}

// ---------------- weight transpose + convert: W (K x N) -> Wt (N x K) bf16 ----------------
__global__ __launch_bounds__(256) void wtrans_kernel(const float* __restrict__ w0,
                                                     const float* __restrict__ w1,
                                                     const float* __restrict__ w2,
                                                     const float* __restrict__ w3,
                                                     u16* __restrict__ wtb) {
  const float* src = blockIdx.z == 0 ? w0 : blockIdx.z == 1 ? w1 : blockIdx.z == 2 ? w2 : w3;
  u16* dst = wtb + (size_t)blockIdx.z * E_DIM * E_DIM;
  __shared__ float tile[32][33];
  int tx = threadIdx.x, ty = threadIdx.y;
  int x = blockIdx.x * 32 + tx;
  int y0 = blockIdx.y * 32;
  for (int j = ty; j < 32; j += 8) tile[j][tx] = src[(size_t)(y0 + j) * E_DIM + x];
  __syncthreads();
  for (int j = ty; j < 32; j += 8)
    dst[(size_t)(blockIdx.x * 32 + j) * E_DIM + blockIdx.y * 32 + tx] = f2b(tile[tx][j]);
}

// ============ 256x256 8-phase GEMM (m201 template, K=1024) ============
// C(M x NTIL*256) = A(M x 1024) * Wt^T + bias; Wt stored [N][1024].
// 512 thr = 8 waves (2M x 4N); per-wave out 128x64. BK=64, 2 k-halves of 32.
// LDS [2 buf][2 kh][256][4 slots of 8 u16] per operand (128 KB total).
// Swizzle: phys slot = logical_slot ^ ((row>>1)&3); staging source inverse-
// swizzled, DMA dest linear (rule #21 both-sides).
// Phase p: [boundary: (vmcnt@p0/p4) + s_barrier] ds_reads; 1 half-tile stage;
// s_barrier; setprio(1); 16 MFMA; setprio(0).  vmcnt(4) = exactly the consumed
// tile's stages drained, 2 half-tiles stay in flight. Tail iter: vmcnt(0)@p4.
template <int MODE>
__global__ __launch_bounds__(512, 1) void gemm8_kernel(const u16* __restrict__ A,
                                                       const u16* __restrict__ Wt,
                                                       const float* __restrict__ b0,
                                                       const float* __restrict__ b1,
                                                       const float* __restrict__ b2,
                                                       void* __restrict__ outBase,
                                                       int M, int NTIL) {
  constexpr int AHALF = 256 * 32;   // u16 per k-half region
  constexpr int ABUF = 2 * AHALF;   // u16 per dbuf (both k-halves)
  __shared__ __align__(16) u16 sm[4 * ABUF];  // A: 2 buf, B: 2 buf = 128 KB
  u16* sA = sm;
  u16* sB = sm + 2 * ABUF;
  u16* epi = sm;                    // epilogue alias [128][264] u16

  // bijective XCD swizzle (m204), nt-fast
  int nwg = gridDim.x;
  int q8 = nwg >> 3, r8 = nwg & 7;
  int orig = blockIdx.x;
  int xcd = orig & 7, loc = orig >> 3;
  int wg = (xcd < r8 ? xcd * (q8 + 1) : r8 * (q8 + 1) + (xcd - r8) * q8) + loc;
  int mt = wg / NTIL, nt = wg - mt * NTIL;
  int m0 = mt * 256, n0 = nt * 256;

  int t = threadIdx.x, lane = t & 63, w = t >> 6;
  int wm = w >> 2, wn = w & 3;
  int lr = lane & 15, g = lane >> 4;

  // staging: thread t instr i covers row i*128+(t>>2), phys slot t&3;
  // source logical slot = (t&3) ^ ((t>>3)&3)
  int ssrc = (((t & 3) ^ ((t >> 3) & 3)) << 3);
  const u16* paA[2];
  const u16* pbB[2];
#pragma unroll
  for (int i = 0; i < 2; i++) {
    int ra = m0 + i * 128 + (t >> 2);
    if (ra >= M) ra = M - 1;
    paA[i] = A + (size_t)ra * 1024 + ssrc;
    pbB[i] = Wt + (size_t)(n0 + i * 128 + (t >> 2)) * 1024 + ssrc;
  }
  int wb = w * 512;  // u16; lane writes +lane*16B

#define STA(bf, kh, kt)                                                          \
  {                                                                              \
    GLOAD16(paA[0] + (kt) * 64 + (kh) * 32, sA + (bf) * ABUF + (kh) * AHALF + wb);       \
    GLOAD16(paA[1] + (kt) * 64 + (kh) * 32, sA + (bf) * ABUF + (kh) * AHALF + 4096 + wb); \
  }
#define STB(bf, kh, kt)                                                          \
  {                                                                              \
    GLOAD16(pbB[0] + (kt) * 64 + (kh) * 32, sB + (bf) * ABUF + (kh) * AHALF + wb);       \
    GLOAD16(pbB[1] + (kt) * 64 + (kh) * 32, sB + (bf) * ABUF + (kh) * AHALF + 4096 + wb); \
  }

  int swz = ((g ^ ((lr >> 1) & 3)) << 3);
  int arow0 = wm * 128 + lr;
  int brow0 = wn * 64 + lr;

#define RD_A(bf, KK, MH, mi) \
  (*(const bf16x8*)&sA[(bf) * ABUF + (KK) * AHALF + (arow0 + (MH) * 64 + (mi) * 16) * 32 + swz])
#define RD_B(bf, KK, nj) \
  (*(const bf16x8*)&sB[(bf) * ABUF + (KK) * AHALF + (brow0 + (nj) * 16) * 32 + swz])

  f4_t acc[8][4] = {};
  bf16x8 bvr0, bvr1, bvr2, bvr3;

#define MMROW(MH, mi, af)                                    \
  acc[(MH) * 4 + (mi)][0] = mfma16(af, bvr0, acc[(MH) * 4 + (mi)][0]); \
  acc[(MH) * 4 + (mi)][1] = mfma16(af, bvr1, acc[(MH) * 4 + (mi)][1]); \
  acc[(MH) * 4 + (mi)][2] = mfma16(af, bvr2, acc[(MH) * 4 + (mi)][2]); \
  acc[(MH) * 4 + (mi)][3] = mfma16(af, bvr3, acc[(MH) * 4 + (mi)][3]);

#define PHASE(bf, MH, KK, LOADB, STG)                        \
  {                                                          \
    bf16x8 af0 = RD_A(bf, KK, MH, 0);                        \
    bf16x8 af1 = RD_A(bf, KK, MH, 1);                        \
    bf16x8 af2 = RD_A(bf, KK, MH, 2);                        \
    bf16x8 af3 = RD_A(bf, KK, MH, 3);                        \
    if (LOADB) {                                             \
      bvr0 = RD_B(bf, KK, 0);                                \
      bvr1 = RD_B(bf, KK, 1);                                \
      bvr2 = RD_B(bf, KK, 2);                                \
      bvr3 = RD_B(bf, KK, 3);                                \
    }                                                        \
    STG;                                                     \
    SBAR;                                                    \
    __builtin_amdgcn_s_setprio(1);                           \
    MMROW(MH, 0, af0);                                       \
    MMROW(MH, 1, af1);                                       \
    MMROW(MH, 2, af2);                                       \
    MMROW(MH, 3, af3);                                       \
    __builtin_amdgcn_s_setprio(0);                           \
  }

  // ---- prologue: buf0 tile0 (both halves) + buf1 tile1 k-half0 ----
  STA(0, 0, 0); STB(0, 0, 0);
  STA(0, 1, 0); STB(0, 1, 0);
  STA(1, 0, 1); STB(1, 0, 1);

  // ---- main loop: iters j=0..6 (tiles 2j, 2j+1), steady-state ----
  for (int j = 0; j < 7; ++j) {
    int k1 = 2 * j + 1, k2 = 2 * j + 2, k3 = 2 * j + 3;
    WAITVM(4);
    SBAR;
    PHASE(0, 0, 0, true, STA(1, 1, k1));   // p0
    SBAR;
    PHASE(0, 1, 0, false, STB(1, 1, k1));  // p1
    SBAR;
    PHASE(0, 0, 1, true, STA(0, 0, k2));   // p2
    SBAR;
    PHASE(0, 1, 1, false, STB(0, 0, k2));  // p3
    WAITVM(4);
    SBAR;
    PHASE(1, 0, 0, true, STA(0, 1, k2));   // p4
    SBAR;
    PHASE(1, 1, 0, false, STB(0, 1, k2));  // p5
    SBAR;
    PHASE(1, 0, 1, true, STA(1, 0, k3));   // p6
    SBAR;
    PHASE(1, 1, 1, false, STB(1, 0, k3));  // p7
  }
  // ---- tail iter j=7 (tiles 14,15): no further staging ----
  {
    WAITVM(4);
    SBAR;
    PHASE(0, 0, 0, true, STA(1, 1, 15));   // p0 completes tile15 staging
    SBAR;
    PHASE(0, 1, 0, false, STB(1, 1, 15));  // p1
    SBAR;
    PHASE(0, 0, 1, true, {});
    SBAR;
    PHASE(0, 1, 1, false, {});
    WAITVM(0);
    SBAR;
    PHASE(1, 0, 0, true, {});
    SBAR;
    PHASE(1, 1, 0, false, {});
    SBAR;
    PHASE(1, 0, 1, true, {});
    SBAR;
    PHASE(1, 1, 1, false, {});
  }
  __syncthreads();  // LDS reuse for epilogue

  if (MODE == 0) {
    // bf16 demux epilogue, 2 passes of 128 rows via LDS
    int tsel = n0 >> 10, ncb = n0 & 1023;
    const float* bp = tsel == 0 ? b0 : (tsel == 1 ? b1 : b2);
    u16* outp = (u16*)outBase + (size_t)tsel * ((size_t)M_ROWS * E_DIM);
#pragma unroll
    for (int h = 0; h < 2; ++h) {
      if (h) __syncthreads();
      if (wm == h) {
#pragma unroll
        for (int nj = 0; nj < 4; nj++) {
          int cl = wn * 64 + nj * 16 + lr;
          float bb = bp[ncb + cl];
#pragma unroll
          for (int mi = 0; mi < 8; mi++) {
#pragma unroll
            for (int r = 0; r < 4; r++)
              epi[(mi * 16 + g * 4 + r) * 264 + cl] = f2b(acc[mi][nj][r] + bb);
          }
        }
      }
      __syncthreads();
      int row = t >> 2, c0 = (t & 3) * 64;
      int m = m0 + h * 128 + row;
      if (m < M) {
        u16* op = outp + (size_t)m * E_DIM + ncb + c0;
        const u16* lp = epi + row * 264 + c0;
#pragma unroll
        for (int qd = 0; qd < 8; qd++) ((uint4*)op)[qd] = ((const uint4*)lp)[qd];
      }
    }
  } else {
    // fp32 direct epilogue
    float* outp = (float*)outBase;
#pragma unroll
    for (int nj = 0; nj < 4; nj++) {
      int n = n0 + wn * 64 + nj * 16 + lr;
      float bb = b0[n];
#pragma unroll
      for (int mi = 0; mi < 8; mi++) {
        int mb = m0 + wm * 128 + mi * 16 + g * 4;
#pragma unroll
        for (int r = 0; r < 4; r++)
          if (mb + r < M) outp[(size_t)(mb + r) * E_DIM + n] = acc[mi][nj][r] + bb;
      }
    }
  }
#undef STA
#undef STB
#undef RD_A
#undef RD_B
#undef MMROW
#undef PHASE
}

// ---------------- global attention, phase 1: per-chunk partials ----------------
__global__ __launch_bounds__(256) void gattn1_kernel(const u16* __restrict__ Qb,
                                                     const u16* __restrict__ Kb,
                                                     const u16* __restrict__ Vb,
                                                     float* __restrict__ part) {
  int c = blockIdx.x;
  int h = blockIdx.y;
  int b = blockIdx.z;
  int t = threadIdx.x;
  __shared__ float qsh[64];
  __shared__ float red[4];
  __shared__ float psh[256];
  __shared__ float cred[4][64];

  size_t base = (size_t)b * L_TOT * E_DIM + h * 64;
  if (t < 64) qsh[t] = b2f(Qb[base + t]);
  __syncthreads();

  int row = c * 256 + t;
  bool valid = row < L_TOT;
  float dot = -1e30f;
  if (valid) {
    const u16* kp = Kb + base + (size_t)row * E_DIM;
    float acc = 0.f;
#pragma unroll
    for (int j = 0; j < 64; j += 8) {
      uint4 kv = *(const uint4*)(kp + j);
      const u16* kk = (const u16*)&kv;
#pragma unroll
      for (int q = 0; q < 8; q++) acc += qsh[j + q] * b2f(kk[q]);
    }
    dot = acc * 0.125f;
  }
  float m = dot;
  for (int mask = 1; mask < 64; mask <<= 1) m = fmaxf(m, __shfl_xor(m, mask));
  if ((t & 63) == 0) red[t >> 6] = m;
  __syncthreads();
  m = fmaxf(fmaxf(red[0], red[1]), fmaxf(red[2], red[3]));
  float p = valid ? __expf(dot - m) : 0.f;
  psh[t] = p;
  float s = p;
  for (int mask = 1; mask < 64; mask <<= 1) s += __shfl_xor(s, mask);
  __syncthreads();
  if ((t & 63) == 0) red[t >> 6] = s;
  __syncthreads();
  s = red[0] + red[1] + red[2] + red[3];

  int d = t & 63, gq = t >> 6;
  float acc = 0.f;
#pragma unroll 4
  for (int i = 0; i < 64; i++) {
    int sl = gq * 64 + i;
    int r2 = c * 256 + sl;
    if (r2 < L_TOT) acc += psh[sl] * b2f(Vb[base + (size_t)r2 * E_DIM + d]);
  }
  cred[gq][d] = acc;
  __syncthreads();
  if (t < 64) {
    float v = cred[0][t] + cred[1][t] + cred[2][t] + cred[3][t];
    float* pp = part + (((size_t)(b * HHEADS + h) * GCHUNKS + c) * 66);
    pp[t] = v;
    if (t == 0) { pp[64] = m; pp[65] = s; }
  }
}

// ---------------- global attention, phase 2: combine chunks ----------------
__global__ __launch_bounds__(64) void gattn2_kernel(const float* __restrict__ part,
                                                    u16* __restrict__ ctxb) {
  int bh = blockIdx.x;
  int b = bh >> 4, h = bh & 15;
  int d = threadIdx.x;
  const float* pp = part + ((size_t)(b * HHEADS + h) * GCHUNKS) * 66;
  float m = -1e30f;
#pragma unroll
  for (int c = 0; c < GCHUNKS; c++) m = fmaxf(m, pp[c * 66 + 64]);
  float stot = 0.f, acc = 0.f;
#pragma unroll
  for (int c = 0; c < GCHUNKS; c++) {
    float w = __expf(pp[c * 66 + 64] - m);
    stot += pp[c * 66 + 65] * w;
    acc += pp[c * 66 + d] * w;
  }
  ctxb[(size_t)b * L_TOT * E_DIM + h * 64 + d] = f2b(acc / stot);
}

// ========== windowed attention v2: swapped-QK^T, in-register softmax ==========
#define VT_IDX(d, k) ((d) * 264 + ((k) ^ ((((d) >> 3) & 7) << 3)))
__global__ __launch_bounds__(256) void wattn_kernel(const u16* __restrict__ Qb,
                                                    const u16* __restrict__ Kb,
                                                    const u16* __restrict__ Vb,
                                                    u16* __restrict__ winctx) {
  int wdw = blockIdx.x;
  int h = blockIdx.y;
  int b = blockIdx.z;

  __shared__ __align__(16) u16 Ks[256 * 64];   // 32 KB, GEMM-style swizzle
  __shared__ __align__(16) u16 Vt[64 * 264];   // 33 KB, [d][k] k-swizzled

  int t = threadIdx.x, lane = t & 63, wv = t >> 6;
  int g = lane >> 4, lr = lane & 15;
  size_t rowbase = (size_t)b * L_TOT + 1 + (size_t)wdw * 128;
  int hoff = h * 64;

  {
    int rsub = t >> 3;
    int ssrc = ((t & 7) ^ (rsub & 7)) * 8;
    const u16* kp = Kb + (rowbase + rsub) * E_DIM + hoff + ssrc;
#pragma unroll
    for (int c = 0; c < 8; c++)
      GLOAD16(kp + (size_t)c * 32 * E_DIM, Ks + c * 2048 + wv * 512);
  }
#pragma unroll
  for (int rep = 0; rep < 8; rep++) {
    int u = rep * 256 + t;
    int i = u >> 3;
    int d0 = (u & 7) * 8;
    uint4 v = *(const uint4*)(Vb + (rowbase + i) * E_DIM + hoff + d0);
    const u16* pv = (const u16*)&v;
#pragma unroll
    for (int j = 0; j < 8; j++) Vt[VT_IDX(d0 + j, i)] = pv[j];
  }
  __syncthreads();

  int slo = (2 * (g & 1)) * 16 + lr;
  int shi = slo + 16;

  for (int grp = 0; grp < 4; grp++) {
    int q0 = grp * 64 + wv * 16;
    const u16* qp = Qb + (rowbase + q0 + lr) * E_DIM + hoff;
    bf16x8 qa0 = *(const bf16x8*)(qp + g * 8);
    bf16x8 qa1 = *(const bf16x8*)(qp + 32 + g * 8);

    f4_t s[16];
    __builtin_amdgcn_s_setprio(1);
#pragma unroll
    for (int ki = 0; ki < 16; ki++) {
      int row = ki * 16 + lr;
      bf16x8 ka0 = *(const bf16x8*)&Ks[row * 64 + ((g ^ (lr & 7)) << 3)];
      bf16x8 ka1 = *(const bf16x8*)&Ks[row * 64 + (((4 + g) ^ (lr & 7)) << 3)];
      f4_t z = {};
      z = mfma16(ka0, qa0, z);
      z = mfma16(ka1, qa1, z);
      s[ki] = z;
    }
    __builtin_amdgcn_s_setprio(0);

    float mx = -1e30f;
#pragma unroll
    for (int ki = 0; ki < 16; ki++) {
      mx = fmaxf(mx, fmaxf(fmaxf(s[ki][0], s[ki][1]), fmaxf(s[ki][2], s[ki][3])));
    }
    mx = fmaxf(mx, __shfl_xor(mx, 16));
    mx = fmaxf(mx, __shfl_xor(mx, 32));
    float mx8 = mx * 0.125f;
    float sum = 0.f;
    u32 pk[16][2];
#pragma unroll
    for (int ki = 0; ki < 16; ki++) {
      float p0 = __expf(fmaf(s[ki][0], 0.125f, -mx8));
      float p1 = __expf(fmaf(s[ki][1], 0.125f, -mx8));
      float p2 = __expf(fmaf(s[ki][2], 0.125f, -mx8));
      float p3 = __expf(fmaf(s[ki][3], 0.125f, -mx8));
      sum += (p0 + p1) + (p2 + p3);
      pk[ki][0] = cvtpk(p0, p1);
      pk[ki][1] = cvtpk(p2, p3);
    }
    sum += __shfl_xor(sum, 16);
    sum += __shfl_xor(sum, 32);
    float inv = 1.0f / sum;

    u32 paw[8][4];
    bool hi = g >= 2;
#pragma unroll
    for (int kt = 0; kt < 8; kt++) {
      u32 v00 = __shfl((int)pk[kt * 2][0], slo);
      u32 v01 = __shfl((int)pk[kt * 2][1], slo);
      u32 v10 = __shfl((int)pk[kt * 2 + 1][0], slo);
      u32 v11 = __shfl((int)pk[kt * 2 + 1][1], slo);
      u32 w00 = __shfl((int)pk[kt * 2][0], shi);
      u32 w01 = __shfl((int)pk[kt * 2][1], shi);
      u32 w10 = __shfl((int)pk[kt * 2 + 1][0], shi);
      u32 w11 = __shfl((int)pk[kt * 2 + 1][1], shi);
      paw[kt][0] = hi ? v10 : v00;
      paw[kt][1] = hi ? v11 : v01;
      paw[kt][2] = hi ? w10 : w00;
      paw[kt][3] = hi ? w11 : w01;
    }

    f4_t o[4] = {};
    __builtin_amdgcn_s_setprio(1);
#pragma unroll
    for (int dtile = 0; dtile < 4; dtile++) {
      int d = dtile * 16 + lr;
      int dswz = (((d >> 3) & 7) << 3);
#pragma unroll
      for (int kt = 0; kt < 8; kt++) {
        int kphys = (kt * 32 + g * 8) ^ dswz;
        bf16x8 vb = *(const bf16x8*)&Vt[d * 264 + kphys];
        o[dtile] = mfma16(*(const bf16x8*)&paw[kt][0], vb, o[dtile]);
      }
    }
    __builtin_amdgcn_s_setprio(0);

    float invr[4];
#pragma unroll
    for (int r = 0; r < 4; r++) invr[r] = __shfl(inv, g * 4 + r);
    size_t orow = (size_t)(b * NWIN + wdw) * 256 + q0;
#pragma unroll
    for (int dtile = 0; dtile < 4; dtile++) {
#pragma unroll
      for (int r = 0; r < 4; r++) {
        winctx[(orow + g * 4 + r) * E_DIM + hoff + dtile * 16 + lr] =
            f2b(o[dtile][r] * invr[r]);
      }
    }
  }
}

// ---------------- overlap-average combine: winctx -> ctxb rows 1..4096 ----------------
__global__ __launch_bounds__(256) void combine_kernel(const u16* __restrict__ winctx,
                                                      u16* __restrict__ ctxb) {
  int idx = blockIdx.x * 256 + threadIdx.x;
  int e0 = (idx & 127) * 8;
  int p = (idx >> 7) & 4095;
  int b = idx >> 19;
  int whi = p >> 7;
  if (whi > 30) whi = 30;
  int off_hi = p - whi * 128;
  int wlo = whi - 1;
  bool has_lo = (wlo >= 0) && (off_hi < 128);

  uint4 vhi = *(const uint4*)(winctx + (((size_t)(b * NWIN + whi) * 256 + off_hi) * E_DIM) + e0);
  const u16* ph = (const u16*)&vhi;
  float vals[8];
#pragma unroll
  for (int j = 0; j < 8; j++) vals[j] = b2f(ph[j]);
  if (has_lo) {
    uint4 vlo = *(const uint4*)(winctx + (((size_t)(b * NWIN + wlo) * 256 + off_hi + 128) * E_DIM) + e0);
    const u16* pl = (const u16*)&vlo;
#pragma unroll
    for (int j = 0; j < 8; j++) vals[j] = (vals[j] + b2f(pl[j])) * 0.5f;
  }
  u16 out[8];
#pragma unroll
  for (int j = 0; j < 8; j++) out[j] = f2b(vals[j]);
  *(uint4*)(ctxb + ((size_t)b * L_TOT + 1 + p) * E_DIM + e0) = *(uint4*)out;
}

// ---------------- launch ----------------
extern "C" void kernel_launch(void* const* d_in, const int* in_sizes, int n_in,
                              void* d_out, int out_size, void* d_ws, size_t ws_size,
                              hipStream_t stream) {
  const float* hs = (const float*)d_in[0];
  const float* Wq = (const float*)d_in[1];
  const float* bq = (const float*)d_in[2];
  const float* Wk = (const float*)d_in[3];
  const float* bk = (const float*)d_in[4];
  const float* Wv = (const float*)d_in[5];
  const float* bv = (const float*)d_in[6];
  const float* Wo = (const float*)d_in[7];
  const float* bo = (const float*)d_in[8];

  const size_t BLE = (size_t)M_ROWS * E_DIM;
  const size_t BLE_B = BLE * 2;
  const size_t EE = (size_t)E_DIM * E_DIM;

  char* ws = (char*)d_ws;
  u16* hsb = (u16*)(ws);
  u16* wtb = (u16*)(ws + BLE_B);
  u16* qkv = (u16*)(ws + BLE_B + 4 * EE * 2);
  u16* Qb = qkv;
  u16* Kb = qkv + BLE;
  u16* Vb = qkv + 2 * BLE;
  u16* ctxb = (u16*)(ws + BLE_B + 4 * EE * 2 + 3 * BLE_B);
  u16* winctx = (u16*)(ws + BLE_B + 4 * EE * 2 + 4 * BLE_B);
  float* gpart = (float*)(ws + BLE_B + 4 * EE * 2 + 4 * BLE_B +
                          (size_t)B_SZ * NWIN * 256 * E_DIM * 2);

  cvt_kernel<<<8194, 256, 0, stream>>>(hs, hsb, (int)(BLE / 4));
  wtrans_kernel<<<dim3(32, 32, 4), dim3(32, 8), 0, stream>>>(Wq, Wk, Wv, Wo, wtb);
  // QKV fused: N = 3072 -> 33 m-tiles x 12 n-tiles = 396 blocks, 512 thr
  gemm8_kernel<0><<<33 * 12, 512, 0, stream>>>(hsb, wtb, bq, bk, bv, qkv, M_ROWS, 12);
  gattn1_kernel<<<dim3(GCHUNKS, HHEADS, B_SZ), 256, 0, stream>>>(Qb, Kb, Vb, gpart);
  gattn2_kernel<<<32, 64, 0, stream>>>(gpart, ctxb);
  wattn_kernel<<<dim3(NWIN, HHEADS, B_SZ), 256, 0, stream>>>(Qb, Kb, Vb, winctx);
  combine_kernel<<<4096, 256, 0, stream>>>(winctx, ctxb);
  // output projection: N = 1024 -> 33 x 4 = 132 blocks
  gemm8_kernel<1><<<33 * 4, 512, 0, stream>>>(ctxb, wtb + 3 * EE, bo, bo, bo, d_out, M_ROWS, 4);
}